// Round 10
// baseline (1820.616 us; speedup 1.0000x reference)
//
#include <hip/hip_runtime.h>
#include <hip/hip_bf16.h>
#include <math.h>

#define DEVFN __device__ __forceinline__

constexpr float BN_INV = 0.99999500003749971f; // 1/sqrt(1+1e-5)

DEVFN float sigm(float x) { return 1.0f / (1.0f + expf(-x)); }

DEVFN unsigned short f2bf(float f) {
    __hip_bfloat16 b = __float2bfloat16(f);
    return *reinterpret_cast<unsigned short*>(&b);
}
DEVFN float bf2f(unsigned short u) {
    unsigned int x = ((unsigned int)u) << 16;
    return *reinterpret_cast<float*>(&x);
}
DEVFN void splitf(float v, unsigned short& h, unsigned short& l) {
    h = f2bf(v);
    l = f2bf(v - bf2f(h));
}
DEVFN unsigned int pack2(unsigned short a, unsigned short b) {
    return (unsigned int)a | ((unsigned int)b << 16);
}
// packed hi/lo: word = hi | lo<<16
DEVFN unsigned int packsplit(float v) {
    unsigned short h, l;
    splitf(v, h, l);
    return pack2(h, l);
}

typedef __attribute__((ext_vector_type(8))) short short8;  // 8 bf16 = 4 VGPRs
typedef __attribute__((ext_vector_type(4))) float f32x4;

// unzip 16 packed (hi|lo<<16) words -> 16 hi shorts + 16 lo shorts in LDS
DEVFN void unzip16(unsigned short* dh, unsigned short* dl,
                   uint4 a0, uint4 a1, uint4 a2, uint4 a3) {
    uint4 h0, h1, l0, l1;
    h0.x = (a0.x & 0xffffu) | (a0.y << 16); l0.x = (a0.x >> 16) | (a0.y & 0xffff0000u);
    h0.y = (a0.z & 0xffffu) | (a0.w << 16); l0.y = (a0.z >> 16) | (a0.w & 0xffff0000u);
    h0.z = (a1.x & 0xffffu) | (a1.y << 16); l0.z = (a1.x >> 16) | (a1.y & 0xffff0000u);
    h0.w = (a1.z & 0xffffu) | (a1.w << 16); l0.w = (a1.z >> 16) | (a1.w & 0xffff0000u);
    h1.x = (a2.x & 0xffffu) | (a2.y << 16); l1.x = (a2.x >> 16) | (a2.y & 0xffff0000u);
    h1.y = (a2.z & 0xffffu) | (a2.w << 16); l1.y = (a2.z >> 16) | (a2.w & 0xffff0000u);
    h1.z = (a3.x & 0xffffu) | (a3.y << 16); l1.z = (a3.x >> 16) | (a3.y & 0xffff0000u);
    h1.w = (a3.z & 0xffffu) | (a3.w << 16); l1.w = (a3.z >> 16) | (a3.w & 0xffff0000u);
    *(uint4*)dh = h0; *(uint4*)(dh + 8) = h1;
    *(uint4*)dl = l0; *(uint4*)(dl + 8) = l1;
}

// async global->LDS, 16B per lane; ldst must be wave-uniform (HW adds lane*16)
#define ASYNC_COPY16(gsrc, ldst)                                                            \
    __builtin_amdgcn_global_load_lds((const __attribute__((address_space(1))) unsigned int*)(gsrc), \
                                     (__attribute__((address_space(3))) unsigned int*)(ldst), 16, 0, 0)

// ---------------- precompute kernels (run every call; ws is re-poisoned) ----------------

// Merged small precompute: [0,384) lstm-weight transpose, [384,640) wh1,
// [640,642) Mp/c1, [642,1154) state init.
__global__ void pre_misc(
    const float* __restrict__ Wih, const float* __restrict__ Whh,
    const float* __restrict__ bih, const float* __restrict__ bhh,
    float* __restrict__ WgT, float* __restrict__ bg,
    const float* __restrict__ pp1W, const float* __restrict__ pp1g,
    float* __restrict__ Wh1T,
    const float* __restrict__ spW, const float* __restrict__ spb,
    const float* __restrict__ pp1b, const float* __restrict__ pp1be,
    float* __restrict__ Mp, float* __restrict__ c1,
    const float* __restrict__ lp, const float* __restrict__ lpr,
    const float* __restrict__ h0, const float* __restrict__ c0,
    const float* __restrict__ embW, const float* __restrict__ embb,
    float* __restrict__ h_st, float* __restrict__ c_st,
    float* __restrict__ curr, float* __restrict__ din) {
    int bid = blockIdx.x, t = threadIdx.x;
    if (bid < 384) {
        int idx = bid * 256 + t;           // 192*512
        int k = idx >> 9, tt = idx & 511;
        WgT[idx] = (k < 64) ? Wih[tt * 64 + k] : Whh[tt * 128 + (k - 64)];
        if (idx < 512) bg[idx] = bih[idx] + bhh[idx];
    } else if (bid < 640) {
        int idx = (bid - 384) * 256 + t;   // 128*512
        int h = idx >> 9, k = idx & 511;
        Wh1T[idx] = pp1W[k * 192 + 64 + h] * (BN_INV * pp1g[k]);
    } else if (bid < 642) {
        int k = (bid - 640) * 256 + t;     // 512
        float m0 = 0.f, m1 = 0.f, c0v = 0.f;
        for (int e = 0; e < 64; e++) {
            float w = pp1W[k * 192 + e];
            m0 += spW[e * 2] * w; m1 += spW[e * 2 + 1] * w; c0v += spb[e] * w;
        }
        float s = BN_INV * pp1g[k];
        Mp[k] = m0 * s; Mp[512 + k] = m1 * s;
        c1[k] = (c0v + pp1b[k]) * s + pp1be[k];
    } else {
        int idx = (bid - 642) * 256 + t;   // 1024*128
        h_st[idx] = h0[idx];
        c_st[idx] = c0[idx];
        if (idx < 1024 * 2) curr[idx] = lp[idx];
        if (idx < 1024 * 64) {
            int n = idx >> 6, e = idx & 63;
            din[idx] = fmaf(lpr[n * 2], embW[e * 2], fmaf(lpr[n * 2 + 1], embW[e * 2 + 1], embb[e]));
        }
    }
}

// Merged weight conversion: [0,2048) pp2->bf16 (XOR-swizzled), [2048,6656) m1 split->packed,
// [6656,7168) m2 split->packed.
__global__ void pre_w(
    const float* __restrict__ pp2W, const float* __restrict__ pp2b,
    const float* __restrict__ pp2g, const float* __restrict__ pp2be,
    unsigned short* __restrict__ W2bf, float* __restrict__ c2v,
    const float* __restrict__ m1W, const float* __restrict__ m1b,
    const float* __restrict__ m1g, const float* __restrict__ m1be,
    unsigned int* __restrict__ M1p, float* __restrict__ cm1,
    const float* __restrict__ m2W, const float* __restrict__ m2b,
    const float* __restrict__ m2g, const float* __restrict__ m2be,
    unsigned int* __restrict__ M2p, float* __restrict__ cm2) {
    int bid = blockIdx.x, t = threadIdx.x;
    if (bid < 2048) {
        int idx = bid * 256 + t;           // 1024*512
        int ko = idx >> 9, k = idx & 511;
        float s = BN_INV * pp2g[ko];
        int outk = (k & ~63) | ((((k >> 3) & 7) ^ (ko & 7)) << 3) | (k & 7);
        W2bf[(ko << 9) + outk] = f2bf(pp2W[idx] * s);
        if (idx < 1024) c2v[idx] = pp2b[idx] * s + pp2be[idx];
    } else if (bid < 6656) {
        int idx = (bid - 2048) * 256 + t;  // 1024*1152
        int ko = idx / 1152;
        float s = BN_INV * m1g[ko];
        M1p[idx] = packsplit(m1W[idx] * s);
        if (idx < 1024) {
            float s2 = BN_INV * m1g[idx];
            cm1[idx] = m1b[idx] * s2 + m1be[idx];
        }
    } else {
        int idx = (bid - 6656) * 256 + t;  // 128*1024
        int ko = idx >> 10;
        float s = BN_INV * m2g[ko];
        M2p[idx] = packsplit(m2W[idx] * s);
        if (idx < 128) {
            float s2 = BN_INV * m2g[idx];
            cm2[idx] = m2b[idx] * s2 + m2be[idx];
        }
    }
}

// ---------------- per-step kernels ----------------

// Fused: LSTM cell (4 peds/block) + rel_pos + curr + din2 + preds + Hp (=h2@Wh1T + c1).
__global__ __launch_bounds__(512) void k_lstm(
    const float* __restrict__ WgT, const float* __restrict__ bg,
    float* __restrict__ h_st, float* __restrict__ c_st,
    float* __restrict__ din, float* __restrict__ curr,
    unsigned int* __restrict__ h2p,
    const float* __restrict__ posW, const float* __restrict__ posb,
    const float* __restrict__ embW, const float* __restrict__ embb,
    const float* __restrict__ Wh1T, const float* __restrict__ c1,
    float* __restrict__ Hp, int doHp,
    float* __restrict__ preds) {
    int n0 = blockIdx.x << 2;
    int t = threadIdx.x;
    __shared__ float xs[4][256];
    __shared__ float gates[4][512];
    __shared__ float h2s[4][128];
    __shared__ float rp[4][2];
#pragma unroll
    for (int u = 0; u < 2; u++) {
        int lin = t + (u << 9);
        int r = lin >> 8, k = lin & 255;
        float v = 0.f;
        if (k < 64) v = din[(n0 + r) * 64 + k];
        else if (k < 192) v = h_st[(n0 + r) * 128 + (k - 64)];
        xs[r][k] = v;
    }
    __syncthreads();
    float a0 = bg[t], a1 = a0, a2 = a0, a3 = a0;
#pragma unroll 4
    for (int k = 0; k < 192; k++) {
        float w = WgT[(k << 9) + t];
        a0 = fmaf(xs[0][k], w, a0);
        a1 = fmaf(xs[1][k], w, a1);
        a2 = fmaf(xs[2][k], w, a2);
        a3 = fmaf(xs[3][k], w, a3);
    }
    gates[0][t] = a0; gates[1][t] = a1; gates[2][t] = a2; gates[3][t] = a3;
    __syncthreads();
    {
        int r = t >> 7, hx = t & 127;
        float ig = sigm(gates[r][hx]);
        float fg = sigm(gates[r][128 + hx]);
        float gg = tanhf(gates[r][256 + hx]);
        float og = sigm(gates[r][384 + hx]);
        float c2 = fmaf(fg, c_st[(n0 + r) * 128 + hx], ig * gg);
        float h2 = og * tanhf(c2);
        c_st[(n0 + r) * 128 + hx] = c2;
        h2p[(n0 + r) * 128 + hx] = packsplit(h2);
        h2s[r][hx] = h2;
    }
    __syncthreads();
    int wv = t >> 6, l = t & 63;
    if (wv < 4) {
        float p0 = fmaf(h2s[wv][l], posW[l], h2s[wv][l + 64] * posW[l + 64]);
        float p1 = fmaf(h2s[wv][l], posW[128 + l], h2s[wv][l + 64] * posW[192 + l]);
#pragma unroll
        for (int off = 32; off > 0; off >>= 1) {
            p0 += __shfl_down(p0, off, 64);
            p1 += __shfl_down(p1, off, 64);
        }
        if (l == 0) { rp[wv][0] = p0 + posb[0]; rp[wv][1] = p1 + posb[1]; }
    }
    __syncthreads();
    if (t < 256) {
        int r = t >> 6, e = t & 63;
        float r0 = rp[r][0], r1 = rp[r][1];
        din[(n0 + r) * 64 + e] = fmaf(r0, embW[e * 2], fmaf(r1, embW[e * 2 + 1], embb[e]));
        if (e == 0) {
            preds[(n0 + r) * 2] = r0; preds[(n0 + r) * 2 + 1] = r1;
            curr[(n0 + r) * 2] += r0; curr[(n0 + r) * 2 + 1] += r1;
        }
    }
    if (doHp) {
        float cc = c1[t];
        float q0 = cc, q1 = cc, q2 = cc, q3 = cc;
#pragma unroll 4
        for (int h = 0; h < 128; h++) {
            float w = Wh1T[(h << 9) + t];
            q0 = fmaf(h2s[0][h], w, q0);
            q1 = fmaf(h2s[1][h], w, q1);
            q2 = fmaf(h2s[2][h], w, q2);
            q3 = fmaf(h2s[3][h], w, q3);
        }
        Hp[((n0 + 0) << 9) + t] = q0;
        Hp[((n0 + 1) << 9) + t] = q1;
        Hp[((n0 + 2) << 9) + t] = q2;
        Hp[((n0 + 3) << 9) + t] = q3;
    }
}

// Fused x1-build + GEMM + max-pool. 256x256 tile, 1024 threads (16 waves), BK=64,
// K=512. A-tile (x1) is built IN-KERNEL from Hp + rx*Mp0 + ry*Mp1 (relu, bf16)
// directly into XOR-swizzled LDS (no global x1 round-trip). B async-staged.
// Both double-buffered. XCD-swizzled linear grid (512): XCD c owns scenes
// {c,c+8,c+16,c+24}. Pool output packed hi/lo.
__global__ __launch_bounds__(1024, 4) void k_pool_f(
    const float* __restrict__ Hp, const float* __restrict__ Mp,
    const float* __restrict__ curr, const unsigned short* __restrict__ W2bf,
    const float* __restrict__ c2v,
    unsigned int* __restrict__ poolp) {
    int bid = blockIdx.x;
    int c = bid & 7, q = bid >> 3;       // q 0..63
    int inner = q & 15, g = q >> 4;      // g 0..3
    int s = (g << 3) + c;
    int rb = inner >> 2;                 // 0..3 -> 8 i's per block
    int koB = (inner & 3) << 8;          // 0,256,512,768
    int t = threadIdx.x;
    int lane = t & 63, wv = t >> 6;      // 16 waves
    int quad = lane >> 4, l15 = lane & 15;
    int wr = wv >> 2, wc = wv & 3;
    int qrow = wr << 6, qcol = wc << 6;
    __shared__ unsigned short As[2][256 * 64];
    __shared__ unsigned short Bs[2][256 * 64];
    __shared__ float rxs[256], rys[256];

    // rx/ry for this block's 8 i x 32 j pairs
    if (t < 256) {
        int iL = t >> 5, j = t & 31;
        int ig = (s << 5) + (rb << 3) + iL;
        int jg = (s << 5) + j;
        float dx = curr[jg * 2] - curr[ig * 2];
        float dy = curr[jg * 2 + 1] - curr[ig * 2 + 1];
        float den = fmaxf(sqrtf(dx * dx + dy * dy), 1e-12f);
        rxs[t] = dx / den; rys[t] = dy / den;
    }
    __syncthreads();

    f32x4 acc[4][4];
#pragma unroll
    for (int a = 0; a < 4; a++)
#pragma unroll
        for (int b = 0; b < 4; b++) acc[a][b] = (f32x4){0.f, 0.f, 0.f, 0.f};

    // --- A build mapping: 4 threads per row, 16 k each ---
    int br_ = t >> 2;                    // row 0..255
    int bj = br_ & 31;
    int k0 = (t & 3) << 4;               // 0,16,32,48
    int c0 = (t & 3) << 1;               // chunk pair
    int sw0 = ((c0 ^ (br_ & 7)) << 3);
    int sw1 = (((c0 + 1) ^ (br_ & 7)) << 3);
    const float* hpRow = Hp + (((s << 5) + bj) << 9);
    float rxv = rxs[br_], ryv = rys[br_];

    // --- B staging mapping ---
    int rlane = lane >> 3;               // 0..7
    int clane = (lane & 7) << 3;
    const unsigned short* gB = W2bf + (size_t)(koB + (wv << 4) + rlane) * 512 + clane;

    // hoisted fragment bases (kt-invariant): pos = ((kt2<<2)+quad) ^ (l15&7)
    const unsigned short* pa0 = &As[0][((qrow + l15) << 6) + ((quad ^ (l15 & 7)) << 3)];
    const unsigned short* pb0 = &Bs[0][((qcol + l15) << 6) + ((quad ^ (l15 & 7)) << 3)];
    const unsigned short* pa1 = &As[0][((qrow + l15) << 6) + (((4 + quad) ^ (l15 & 7)) << 3)];
    const unsigned short* pb1 = &Bs[0][((qcol + l15) << 6) + (((4 + quad) ^ (l15 & 7)) << 3)];

#define BUILD_A(kt, buf)                                                        \
    do {                                                                        \
        unsigned short* baseA = &As[buf][br_ << 6];                             \
        int kk = (kt) + k0;                                                     \
        float4 h0 = *(const float4*)(hpRow + kk);                               \
        float4 h1 = *(const float4*)(hpRow + kk + 4);                           \
        float4 h2v = *(const float4*)(hpRow + kk + 8);                          \
        float4 h3 = *(const float4*)(hpRow + kk + 12);                          \
        float4 p0 = *(const float4*)(Mp + kk);                                  \
        float4 p1 = *(const float4*)(Mp + kk + 4);                              \
        float4 p2 = *(const float4*)(Mp + kk + 8);                              \
        float4 p3 = *(const float4*)(Mp + kk + 12);                             \
        float4 q0 = *(const float4*)(Mp + 512 + kk);                            \
        float4 q1 = *(const float4*)(Mp + 512 + kk + 4);                        \
        float4 q2 = *(const float4*)(Mp + 512 + kk + 8);                        \
        float4 q3 = *(const float4*)(Mp + 512 + kk + 12);                       \
        uint4 o0, o1;                                                           \
        o0.x = pack2(f2bf(fmaxf(fmaf(rxv, p0.x, fmaf(ryv, q0.x, h0.x)), 0.f)),  \
                     f2bf(fmaxf(fmaf(rxv, p0.y, fmaf(ryv, q0.y, h0.y)), 0.f))); \
        o0.y = pack2(f2bf(fmaxf(fmaf(rxv, p0.z, fmaf(ryv, q0.z, h0.z)), 0.f)),  \
                     f2bf(fmaxf(fmaf(rxv, p0.w, fmaf(ryv, q0.w, h0.w)), 0.f))); \
        o0.z = pack2(f2bf(fmaxf(fmaf(rxv, p1.x, fmaf(ryv, q1.x, h1.x)), 0.f)),  \
                     f2bf(fmaxf(fmaf(rxv, p1.y, fmaf(ryv, q1.y, h1.y)), 0.f))); \
        o0.w = pack2(f2bf(fmaxf(fmaf(rxv, p1.z, fmaf(ryv, q1.z, h1.z)), 0.f)),  \
                     f2bf(fmaxf(fmaf(rxv, p1.w, fmaf(ryv, q1.w, h1.w)), 0.f))); \
        o1.x = pack2(f2bf(fmaxf(fmaf(rxv, p2.x, fmaf(ryv, q2.x, h2v.x)), 0.f)), \
                     f2bf(fmaxf(fmaf(rxv, p2.y, fmaf(ryv, q2.y, h2v.y)), 0.f))); \
        o1.y = pack2(f2bf(fmaxf(fmaf(rxv, p2.z, fmaf(ryv, q2.z, h2v.z)), 0.f)), \
                     f2bf(fmaxf(fmaf(rxv, p2.w, fmaf(ryv, q2.w, h2v.w)), 0.f))); \
        o1.z = pack2(f2bf(fmaxf(fmaf(rxv, p3.x, fmaf(ryv, q3.x, h3.x)), 0.f)),  \
                     f2bf(fmaxf(fmaf(rxv, p3.y, fmaf(ryv, q3.y, h3.y)), 0.f))); \
        o1.w = pack2(f2bf(fmaxf(fmaf(rxv, p3.z, fmaf(ryv, q3.z, h3.z)), 0.f)),  \
                     f2bf(fmaxf(fmaf(rxv, p3.w, fmaf(ryv, q3.w, h3.w)), 0.f))); \
        *(uint4*)(baseA + sw0) = o0;                                            \
        *(uint4*)(baseA + sw1) = o1;                                            \
    } while (0)

#define STAGE_B(kt, buf)                                              \
    do {                                                              \
        unsigned short* lB = &Bs[buf][wv << 10];                      \
        ASYNC_COPY16(gB + (kt), lB);                                  \
        ASYNC_COPY16(gB + (kt) + 8 * 512, lB + (8 << 6));             \
    } while (0)

    STAGE_B(0, 0);
    BUILD_A(0, 0);
    __syncthreads();
    for (int i = 0; i < 8; i++) {
        if (i < 7) {
            STAGE_B((i + 1) << 6, (i + 1) & 1);
            BUILD_A((i + 1) << 6, (i + 1) & 1);
        }
        int off = (i & 1) << 14;       // buffer stride 256*64 shorts
        short8 aF[4], bF[4];
#pragma unroll
        for (int a = 0; a < 4; a++) aF[a] = *(const short8*)(pa0 + off + (a << 10));
#pragma unroll
        for (int b = 0; b < 4; b++) bF[b] = *(const short8*)(pb0 + off + (b << 10));
#pragma unroll
        for (int a = 0; a < 4; a++)
#pragma unroll
            for (int b = 0; b < 4; b++)
                acc[a][b] = __builtin_amdgcn_mfma_f32_16x16x32_bf16(aF[a], bF[b], acc[a][b], 0, 0, 0);
#pragma unroll
        for (int a = 0; a < 4; a++) aF[a] = *(const short8*)(pa1 + off + (a << 10));
#pragma unroll
        for (int b = 0; b < 4; b++) bF[b] = *(const short8*)(pb1 + off + (b << 10));
#pragma unroll
        for (int a = 0; a < 4; a++)
#pragma unroll
            for (int b = 0; b < 4; b++)
                acc[a][b] = __builtin_amdgcn_mfma_f32_16x16x32_bf16(aF[a], bF[b], acc[a][b], 0, 0, 0);
        __syncthreads();
    }
#undef BUILD_A
#undef STAGE_B

    // max over j: quadrant rows = 2 i's (32 j each); a=0,1 -> i0, a=2,3 -> i0+1
    float mx0[4], mx1[4];
#pragma unroll
    for (int b = 0; b < 4; b++) {
        float m = acc[0][b].x;
#pragma unroll
        for (int a = 0; a < 2; a++) {
            m = fmaxf(m, acc[a][b].x); m = fmaxf(m, acc[a][b].y);
            m = fmaxf(m, acc[a][b].z); m = fmaxf(m, acc[a][b].w);
        }
        m = fmaxf(m, __shfl_xor(m, 16));
        m = fmaxf(m, __shfl_xor(m, 32));
        mx0[b] = m;
        float n = acc[2][b].x;
#pragma unroll
        for (int a = 2; a < 4; a++) {
            n = fmaxf(n, acc[a][b].x); n = fmaxf(n, acc[a][b].y);
            n = fmaxf(n, acc[a][b].z); n = fmaxf(n, acc[a][b].w);
        }
        n = fmaxf(n, __shfl_xor(n, 16));
        n = fmaxf(n, __shfl_xor(n, 32));
        mx1[b] = n;
    }
    float v0 = (quad == 0) ? mx0[0] : (quad == 1) ? mx0[1] : (quad == 2) ? mx0[2] : mx0[3];
    float v1 = (quad == 0) ? mx1[0] : (quad == 1) ? mx1[1] : (quad == 2) ? mx1[2] : mx1[3];
    int col = koB + qcol + (quad << 4) + l15;
    int i0 = (rb << 3) + (wr << 1);
    int si0 = (s << 5) + i0;
    float bias = c2v[col];
    poolp[si0 * 1024 + col] = packsplit(fmaxf(v0 + bias, 0.f));
    poolp[(si0 + 1) * 1024 + col] = packsplit(fmaxf(v1 + bias, 0.f));
}

// m1 via bf16x3 MFMA. Block: 64 rows x 64 ko, BK=64, K=1152, sync staging from
// PACKED operands. Grid dim3(16,16): x=ko-group (XCD gets 2 ko-groups -> B L2-resident).
__global__ __launch_bounds__(256) void k_m1_mfma(
    const unsigned int* __restrict__ h2p, const unsigned int* __restrict__ poolp,
    const unsigned int* __restrict__ M1p, const float* __restrict__ cm1,
    unsigned int* __restrict__ dh1p) {
    int rowBase = blockIdx.y << 6;
    int koBase = blockIdx.x << 6;
    int t = threadIdx.x;
    int lane = t & 63, wv = t >> 6;
    int quad = lane >> 4, l15 = lane & 15;
    int qrow = (wv >> 1) << 5, qcol = (wv & 1) << 5;
    __shared__ unsigned short Ah[64 * 72], Al[64 * 72], Bh[64 * 72], Bl[64 * 72];
    f32x4 acc[2][2];
#pragma unroll
    for (int a = 0; a < 2; a++)
#pragma unroll
        for (int b = 0; b < 2; b++) acc[a][b] = (f32x4){0.f, 0.f, 0.f, 0.f};

    int ar = t >> 2, ak = (t & 3) << 4;   // 64 rows x 64 k, 16 k-elements/thread

    for (int kt = 0; kt < 1152; kt += 64) {
        {
            const unsigned int* srcA = (kt < 128)
                ? h2p + (rowBase + ar) * 128 + kt + ak
                : poolp + (rowBase + ar) * 1024 + (kt - 128) + ak;
            uint4 a0 = ((const uint4*)srcA)[0];
            uint4 a1 = ((const uint4*)srcA)[1];
            uint4 a2 = ((const uint4*)srcA)[2];
            uint4 a3 = ((const uint4*)srcA)[3];
            const unsigned int* srcB = M1p + (koBase + ar) * 1152 + kt + ak;
            uint4 b0 = ((const uint4*)srcB)[0];
            uint4 b1 = ((const uint4*)srcB)[1];
            uint4 b2 = ((const uint4*)srcB)[2];
            uint4 b3 = ((const uint4*)srcB)[3];
            unzip16(&Ah[ar * 72 + ak], &Al[ar * 72 + ak], a0, a1, a2, a3);
            unzip16(&Bh[ar * 72 + ak], &Bl[ar * 72 + ak], b0, b1, b2, b3);
        }
        __syncthreads();
#pragma unroll
        for (int kk2 = 0; kk2 < 2; kk2++) {
            int kc = ((kk2 << 2) | quad) << 3;
            short8 bH[2], bL[2];
#pragma unroll
            for (int b = 0; b < 2; b++) {
                int boff = (qcol + (b << 4) + l15) * 72 + kc;
                bH[b] = *(const short8*)(&Bh[boff]);
                bL[b] = *(const short8*)(&Bl[boff]);
            }
#pragma unroll
            for (int a = 0; a < 2; a++) {
                int aoff = (qrow + (a << 4) + l15) * 72 + kc;
                short8 aH = *(const short8*)(&Ah[aoff]);
                short8 aL = *(const short8*)(&Al[aoff]);
#pragma unroll
                for (int b = 0; b < 2; b++) {
                    acc[a][b] = __builtin_amdgcn_mfma_f32_16x16x32_bf16(aH, bH[b], acc[a][b], 0, 0, 0);
                    acc[a][b] = __builtin_amdgcn_mfma_f32_16x16x32_bf16(aH, bL[b], acc[a][b], 0, 0, 0);
                    acc[a][b] = __builtin_amdgcn_mfma_f32_16x16x32_bf16(aL, bH[b], acc[a][b], 0, 0, 0);
                }
            }
        }
        __syncthreads();
    }
#pragma unroll
    for (int b = 0; b < 2; b++) {
        int col = koBase + qcol + (b << 4) + l15;
        float bias = cm1[col];
#pragma unroll
        for (int a = 0; a < 2; a++) {
#pragma unroll
            for (int rg = 0; rg < 4; rg++) {
                int row = rowBase + qrow + (a << 4) + (quad << 2) + rg;
                dh1p[row * 1024 + col] = packsplit(fmaxf(acc[a][b][rg] + bias, 0.f));
            }
        }
    }
}

// m2 via bf16x3 MFMA: Block: 32 rows x 128 ko, K=1024. Grid 32. Packed operands.
__global__ __launch_bounds__(256) void k_m2_mfma(
    const unsigned int* __restrict__ dh1p, const unsigned int* __restrict__ M2p,
    const float* __restrict__ cm2, float* __restrict__ h_st) {
    int rowBase = blockIdx.x << 5;
    int t = threadIdx.x;
    int lane = t & 63, wv = t >> 6;
    int quad = lane >> 4, l15 = lane & 15;
    int qrow = (wv >> 1) << 4;   // 0 or 16
    int qcol = (wv & 1) << 6;    // 0 or 64
    __shared__ unsigned short Ah[32 * 40], Al[32 * 40], Bh[128 * 40], Bl[128 * 40];
    f32x4 acc[4];
#pragma unroll
    for (int b = 0; b < 4; b++) acc[b] = (f32x4){0.f, 0.f, 0.f, 0.f};

    int ar = t >> 3, ak = (t & 7) << 2;   // A: 32 rows x 32 k, 4 elements/thread
    int br = t >> 1, bk = (t & 1) << 4;   // B: 128 ko x 32 k, 16 elements/thread

    for (int kt = 0; kt < 1024; kt += 32) {
        {
            uint4 av = *(const uint4*)(dh1p + (rowBase + ar) * 1024 + kt + ak);
            uint2 hi = make_uint2((av.x & 0xffffu) | (av.y << 16),
                                  (av.z & 0xffffu) | (av.w << 16));
            uint2 lo = make_uint2((av.x >> 16) | (av.y & 0xffff0000u),
                                  (av.z >> 16) | (av.w & 0xffff0000u));
            *(uint2*)&Ah[ar * 40 + ak] = hi;
            *(uint2*)&Al[ar * 40 + ak] = lo;
        }
        {
            const unsigned int* srcB = M2p + br * 1024 + kt + bk;
            uint4 b0 = ((const uint4*)srcB)[0];
            uint4 b1 = ((const uint4*)srcB)[1];
            uint4 b2 = ((const uint4*)srcB)[2];
            uint4 b3 = ((const uint4*)srcB)[3];
            unzip16(&Bh[br * 40 + bk], &Bl[br * 40 + bk], b0, b1, b2, b3);
        }
        __syncthreads();
        {
            int aoff = (qrow + l15) * 40 + (quad << 3);
            short8 aH = *(const short8*)(&Ah[aoff]);
            short8 aL = *(const short8*)(&Al[aoff]);
#pragma unroll
            for (int b = 0; b < 4; b++) {
                int boff = (qcol + (b << 4) + l15) * 40 + (quad << 3);
                short8 bH = *(const short8*)(&Bh[boff]);
                short8 bL = *(const short8*)(&Bl[boff]);
                acc[b] = __builtin_amdgcn_mfma_f32_16x16x32_bf16(aH, bH, acc[b], 0, 0, 0);
                acc[b] = __builtin_amdgcn_mfma_f32_16x16x32_bf16(aH, bL, acc[b], 0, 0, 0);
                acc[b] = __builtin_amdgcn_mfma_f32_16x16x32_bf16(aL, bH, acc[b], 0, 0, 0);
            }
        }
        __syncthreads();
    }
#pragma unroll
    for (int b = 0; b < 4; b++) {
        int col = qcol + (b << 4) + l15;
        float bias = cm2[col];
#pragma unroll
        for (int rg = 0; rg < 4; rg++) {
            int row = rowBase + qrow + (quad << 2) + rg;
            h_st[row * 128 + col] = fmaxf(acc[b][rg] + bias, 0.f);
        }
    }
}

// ---------------- launch ----------------

extern "C" void kernel_launch(void* const* d_in, const int* in_sizes, int n_in,
                              void* d_out, int out_size, void* d_ws, size_t ws_size,
                              hipStream_t stream) {
    const float* last_pos     = (const float*)d_in[0];
    const float* last_pos_rel = (const float*)d_in[1];
    const float* h0   = (const float*)d_in[2];
    const float* c0   = (const float*)d_in[3];
    const float* emb_W = (const float*)d_in[5];
    const float* emb_b = (const float*)d_in[6];
    const float* lstm_Wih = (const float*)d_in[7];
    const float* lstm_Whh = (const float*)d_in[8];
    const float* lstm_bih = (const float*)d_in[9];
    const float* lstm_bhh = (const float*)d_in[10];
    const float* pos_W = (const float*)d_in[11];
    const float* pos_b = (const float*)d_in[12];
    const float* sp_W  = (const float*)d_in[13];
    const float* sp_b  = (const float*)d_in[14];
    const float* pp1_W = (const float*)d_in[15];
    const float* pp1_b = (const float*)d_in[16];
    const float* pp1_g = (const float*)d_in[17];
    const float* pp1_be= (const float*)d_in[18];
    const float* pp2_W = (const float*)d_in[19];
    const float* pp2_b = (const float*)d_in[20];
    const float* pp2_g = (const float*)d_in[21];
    const float* pp2_be= (const float*)d_in[22];
    const float* m1_W  = (const float*)d_in[23];
    const float* m1_b  = (const float*)d_in[24];
    const float* m1_g  = (const float*)d_in[25];
    const float* m1_be = (const float*)d_in[26];
    const float* m2_W  = (const float*)d_in[27];
    const float* m2_b  = (const float*)d_in[28];
    const float* m2_g  = (const float*)d_in[29];
    const float* m2_be = (const float*)d_in[30];
    float* out = (float*)d_out;

    float* p = (float*)d_ws;
    float* WgT  = p; p += 192 * 512;
    float* bg   = p; p += 512;
    float* Wh1T = p; p += 128 * 512;
    float* Mp   = p; p += 2 * 512;
    float* c1   = p; p += 512;
    unsigned short* W2bf = (unsigned short*)p; p += 512 * 1024 / 2;
    float* c2v  = p; p += 1024;
    unsigned int* M1p = (unsigned int*)p; p += 1024 * 1152;
    float* cm1  = p; p += 1024;
    unsigned int* M2p = (unsigned int*)p; p += 128 * 1024;
    float* cm2  = p; p += 128;
    float* h_st = p; p += 1024 * 128;
    float* c_st = p; p += 1024 * 128;
    unsigned int* h2p = (unsigned int*)p; p += 1024 * 128;
    float* curr = p; p += 1024 * 2;
    float* din  = p; p += 1024 * 64;
    float* Hp   = p; p += 1024 * 512;
    unsigned int* poolp = (unsigned int*)p; p += 1024 * 1024;
    unsigned int* dh1p = (unsigned int*)p; p += 1024 * 1024;

    pre_misc<<<1154, 256, 0, stream>>>(lstm_Wih, lstm_Whh, lstm_bih, lstm_bhh, WgT, bg,
                                       pp1_W, pp1_g, Wh1T,
                                       sp_W, sp_b, pp1_b, pp1_be, Mp, c1,
                                       last_pos, last_pos_rel, h0, c0, emb_W, emb_b,
                                       h_st, c_st, curr, din);
    pre_w<<<7168, 256, 0, stream>>>(pp2_W, pp2_b, pp2_g, pp2_be, W2bf, c2v,
                                    m1_W, m1_b, m1_g, m1_be, M1p, cm1,
                                    m2_W, m2_b, m2_g, m2_be, M2p, cm2);

    for (int t = 0; t < 12; t++) {
        k_lstm<<<256, 512, 0, stream>>>(WgT, bg, h_st, c_st, din, curr, h2p,
                                        pos_W, pos_b, emb_W, emb_b,
                                        Wh1T, c1, Hp, (t < 11) ? 1 : 0, out + t * 2048);
        if (t == 11) break;
        k_pool_f<<<512, 1024, 0, stream>>>(Hp, Mp, curr, W2bf, c2v, poolp);
        k_m1_mfma<<<dim3(16, 16), 256, 0, stream>>>(h2p, poolp, M1p, cm1, dh1p);
        k_m2_mfma<<<32, 256, 0, stream>>>(dh1p, M2p, cm2, h_st);
    }
}

// Round 11
// 1494.982 us; speedup vs baseline: 1.2178x; 1.2178x over previous
//
#include <hip/hip_runtime.h>
#include <hip/hip_bf16.h>
#include <math.h>

#define DEVFN __device__ __forceinline__

constexpr float BN_INV = 0.99999500003749971f; // 1/sqrt(1+1e-5)

DEVFN float sigm(float x) { return 1.0f / (1.0f + expf(-x)); }

DEVFN unsigned short f2bf(float f) {
    __hip_bfloat16 b = __float2bfloat16(f);
    return *reinterpret_cast<unsigned short*>(&b);
}
DEVFN float bf2f(unsigned short u) {
    unsigned int x = ((unsigned int)u) << 16;
    return *reinterpret_cast<float*>(&x);
}
DEVFN void splitf(float v, unsigned short& h, unsigned short& l) {
    h = f2bf(v);
    l = f2bf(v - bf2f(h));
}
DEVFN unsigned int pack2(unsigned short a, unsigned short b) {
    return (unsigned int)a | ((unsigned int)b << 16);
}
// packed hi/lo: word = hi | lo<<16
DEVFN unsigned int packsplit(float v) {
    unsigned short h, l;
    splitf(v, h, l);
    return pack2(h, l);
}

typedef __attribute__((ext_vector_type(8))) short short8;  // 8 bf16 = 4 VGPRs
typedef __attribute__((ext_vector_type(4))) float f32x4;

// unzip 16 packed (hi|lo<<16) words -> 16 hi shorts + 16 lo shorts in LDS
DEVFN void unzip16(unsigned short* dh, unsigned short* dl,
                   uint4 a0, uint4 a1, uint4 a2, uint4 a3) {
    uint4 h0, h1, l0, l1;
    h0.x = (a0.x & 0xffffu) | (a0.y << 16); l0.x = (a0.x >> 16) | (a0.y & 0xffff0000u);
    h0.y = (a0.z & 0xffffu) | (a0.w << 16); l0.y = (a0.z >> 16) | (a0.w & 0xffff0000u);
    h0.z = (a1.x & 0xffffu) | (a1.y << 16); l0.z = (a1.x >> 16) | (a1.y & 0xffff0000u);
    h0.w = (a1.z & 0xffffu) | (a1.w << 16); l0.w = (a1.z >> 16) | (a1.w & 0xffff0000u);
    h1.x = (a2.x & 0xffffu) | (a2.y << 16); l1.x = (a2.x >> 16) | (a2.y & 0xffff0000u);
    h1.y = (a2.z & 0xffffu) | (a2.w << 16); l1.y = (a2.z >> 16) | (a2.w & 0xffff0000u);
    h1.z = (a3.x & 0xffffu) | (a3.y << 16); l1.z = (a3.x >> 16) | (a3.y & 0xffff0000u);
    h1.w = (a3.z & 0xffffu) | (a3.w << 16); l1.w = (a3.z >> 16) | (a3.w & 0xffff0000u);
    *(uint4*)dh = h0; *(uint4*)(dh + 8) = h1;
    *(uint4*)dl = l0; *(uint4*)(dl + 8) = l1;
}

// async global->LDS, 16B per lane; ldst must be wave-uniform (HW adds lane*16)
#define ASYNC_COPY16(gsrc, ldst)                                                            \
    __builtin_amdgcn_global_load_lds((const __attribute__((address_space(1))) unsigned int*)(gsrc), \
                                     (__attribute__((address_space(3))) unsigned int*)(ldst), 16, 0, 0)

// ---------------- precompute kernels (run every call; ws is re-poisoned) ----------------

// Merged small precompute: [0,384) lstm-weight transpose, [384,640) wh1,
// [640,642) Mp/c1, [642,1154) state init.
__global__ void pre_misc(
    const float* __restrict__ Wih, const float* __restrict__ Whh,
    const float* __restrict__ bih, const float* __restrict__ bhh,
    float* __restrict__ WgT, float* __restrict__ bg,
    const float* __restrict__ pp1W, const float* __restrict__ pp1g,
    float* __restrict__ Wh1T,
    const float* __restrict__ spW, const float* __restrict__ spb,
    const float* __restrict__ pp1b, const float* __restrict__ pp1be,
    float* __restrict__ Mp, float* __restrict__ c1,
    const float* __restrict__ lp, const float* __restrict__ lpr,
    const float* __restrict__ h0, const float* __restrict__ c0,
    const float* __restrict__ embW, const float* __restrict__ embb,
    float* __restrict__ h_st, float* __restrict__ c_st,
    float* __restrict__ curr, float* __restrict__ din) {
    int bid = blockIdx.x, t = threadIdx.x;
    if (bid < 384) {
        int idx = bid * 256 + t;           // 192*512
        int k = idx >> 9, tt = idx & 511;
        WgT[idx] = (k < 64) ? Wih[tt * 64 + k] : Whh[tt * 128 + (k - 64)];
        if (idx < 512) bg[idx] = bih[idx] + bhh[idx];
    } else if (bid < 640) {
        int idx = (bid - 384) * 256 + t;   // 128*512
        int h = idx >> 9, k = idx & 511;
        Wh1T[idx] = pp1W[k * 192 + 64 + h] * (BN_INV * pp1g[k]);
    } else if (bid < 642) {
        int k = (bid - 640) * 256 + t;     // 512
        float m0 = 0.f, m1 = 0.f, c0v = 0.f;
        for (int e = 0; e < 64; e++) {
            float w = pp1W[k * 192 + e];
            m0 += spW[e * 2] * w; m1 += spW[e * 2 + 1] * w; c0v += spb[e] * w;
        }
        float s = BN_INV * pp1g[k];
        Mp[k] = m0 * s; Mp[512 + k] = m1 * s;
        c1[k] = (c0v + pp1b[k]) * s + pp1be[k];
    } else {
        int idx = (bid - 642) * 256 + t;   // 1024*128
        h_st[idx] = h0[idx];
        c_st[idx] = c0[idx];
        if (idx < 1024 * 2) curr[idx] = lp[idx];
        if (idx < 1024 * 64) {
            int n = idx >> 6, e = idx & 63;
            din[idx] = fmaf(lpr[n * 2], embW[e * 2], fmaf(lpr[n * 2 + 1], embW[e * 2 + 1], embb[e]));
        }
    }
}

// Merged weight conversion: [0,2048) pp2->bf16 (XOR-swizzled), [2048,6656) m1 split->packed,
// [6656,7168) m2 split->packed.
__global__ void pre_w(
    const float* __restrict__ pp2W, const float* __restrict__ pp2b,
    const float* __restrict__ pp2g, const float* __restrict__ pp2be,
    unsigned short* __restrict__ W2bf, float* __restrict__ c2v,
    const float* __restrict__ m1W, const float* __restrict__ m1b,
    const float* __restrict__ m1g, const float* __restrict__ m1be,
    unsigned int* __restrict__ M1p, float* __restrict__ cm1,
    const float* __restrict__ m2W, const float* __restrict__ m2b,
    const float* __restrict__ m2g, const float* __restrict__ m2be,
    unsigned int* __restrict__ M2p, float* __restrict__ cm2) {
    int bid = blockIdx.x, t = threadIdx.x;
    if (bid < 2048) {
        int idx = bid * 256 + t;           // 1024*512
        int ko = idx >> 9, k = idx & 511;
        float s = BN_INV * pp2g[ko];
        int outk = (k & ~63) | ((((k >> 3) & 7) ^ (ko & 7)) << 3) | (k & 7);
        W2bf[(ko << 9) + outk] = f2bf(pp2W[idx] * s);
        if (idx < 1024) c2v[idx] = pp2b[idx] * s + pp2be[idx];
    } else if (bid < 6656) {
        int idx = (bid - 2048) * 256 + t;  // 1024*1152
        int ko = idx / 1152;
        float s = BN_INV * m1g[ko];
        M1p[idx] = packsplit(m1W[idx] * s);
        if (idx < 1024) {
            float s2 = BN_INV * m1g[idx];
            cm1[idx] = m1b[idx] * s2 + m1be[idx];
        }
    } else {
        int idx = (bid - 6656) * 256 + t;  // 128*1024
        int ko = idx >> 10;
        float s = BN_INV * m2g[ko];
        M2p[idx] = packsplit(m2W[idx] * s);
        if (idx < 128) {
            float s2 = BN_INV * m2g[idx];
            cm2[idx] = m2b[idx] * s2 + m2be[idx];
        }
    }
}

// ---------------- per-step kernels ----------------

// Fused: LSTM cell (4 peds/block) + rel_pos + curr + din2 + preds + Hp (=h2@Wh1T + c1).
__global__ __launch_bounds__(512) void k_lstm(
    const float* __restrict__ WgT, const float* __restrict__ bg,
    float* __restrict__ h_st, float* __restrict__ c_st,
    float* __restrict__ din, float* __restrict__ curr,
    unsigned int* __restrict__ h2p,
    const float* __restrict__ posW, const float* __restrict__ posb,
    const float* __restrict__ embW, const float* __restrict__ embb,
    const float* __restrict__ Wh1T, const float* __restrict__ c1,
    float* __restrict__ Hp, int doHp,
    float* __restrict__ preds) {
    int n0 = blockIdx.x << 2;
    int t = threadIdx.x;
    __shared__ float xs[4][256];
    __shared__ float gates[4][512];
    __shared__ float h2s[4][128];
    __shared__ float rp[4][2];
#pragma unroll
    for (int u = 0; u < 2; u++) {
        int lin = t + (u << 9);
        int r = lin >> 8, k = lin & 255;
        float v = 0.f;
        if (k < 64) v = din[(n0 + r) * 64 + k];
        else if (k < 192) v = h_st[(n0 + r) * 128 + (k - 64)];
        xs[r][k] = v;
    }
    __syncthreads();
    float a0 = bg[t], a1 = a0, a2 = a0, a3 = a0;
#pragma unroll 4
    for (int k = 0; k < 192; k++) {
        float w = WgT[(k << 9) + t];
        a0 = fmaf(xs[0][k], w, a0);
        a1 = fmaf(xs[1][k], w, a1);
        a2 = fmaf(xs[2][k], w, a2);
        a3 = fmaf(xs[3][k], w, a3);
    }
    gates[0][t] = a0; gates[1][t] = a1; gates[2][t] = a2; gates[3][t] = a3;
    __syncthreads();
    {
        int r = t >> 7, hx = t & 127;
        float ig = sigm(gates[r][hx]);
        float fg = sigm(gates[r][128 + hx]);
        float gg = tanhf(gates[r][256 + hx]);
        float og = sigm(gates[r][384 + hx]);
        float c2 = fmaf(fg, c_st[(n0 + r) * 128 + hx], ig * gg);
        float h2 = og * tanhf(c2);
        c_st[(n0 + r) * 128 + hx] = c2;
        h2p[(n0 + r) * 128 + hx] = packsplit(h2);
        h2s[r][hx] = h2;
    }
    __syncthreads();
    int wv = t >> 6, l = t & 63;
    if (wv < 4) {
        float p0 = fmaf(h2s[wv][l], posW[l], h2s[wv][l + 64] * posW[l + 64]);
        float p1 = fmaf(h2s[wv][l], posW[128 + l], h2s[wv][l + 64] * posW[192 + l]);
#pragma unroll
        for (int off = 32; off > 0; off >>= 1) {
            p0 += __shfl_down(p0, off, 64);
            p1 += __shfl_down(p1, off, 64);
        }
        if (l == 0) { rp[wv][0] = p0 + posb[0]; rp[wv][1] = p1 + posb[1]; }
    }
    __syncthreads();
    if (t < 256) {
        int r = t >> 6, e = t & 63;
        float r0 = rp[r][0], r1 = rp[r][1];
        din[(n0 + r) * 64 + e] = fmaf(r0, embW[e * 2], fmaf(r1, embW[e * 2 + 1], embb[e]));
        if (e == 0) {
            preds[(n0 + r) * 2] = r0; preds[(n0 + r) * 2 + 1] = r1;
            curr[(n0 + r) * 2] += r0; curr[(n0 + r) * 2 + 1] += r1;
        }
    }
    if (doHp) {
        float cc = c1[t];
        float q0 = cc, q1 = cc, q2 = cc, q3 = cc;
#pragma unroll 4
        for (int h = 0; h < 128; h++) {
            float w = Wh1T[(h << 9) + t];
            q0 = fmaf(h2s[0][h], w, q0);
            q1 = fmaf(h2s[1][h], w, q1);
            q2 = fmaf(h2s[2][h], w, q2);
            q3 = fmaf(h2s[3][h], w, q3);
        }
        Hp[((n0 + 0) << 9) + t] = q0;
        Hp[((n0 + 1) << 9) + t] = q1;
        Hp[((n0 + 2) << 9) + t] = q2;
        Hp[((n0 + 3) << 9) + t] = q3;
    }
}

// Build x1 bf16 once per step, XOR-swizzled within each 64-k tile (chunk c at c^(j&7)).
// XCD-swizzled grid: scene s on XCD s%8 so x1 lands in the consumer's L2.
__global__ __launch_bounds__(256) void k_x1(
    const float* __restrict__ Hp, const float* __restrict__ Mp,
    const float* __restrict__ curr, unsigned short* __restrict__ x1g) {
    int bid = blockIdx.x;
    int c = bid & 7, q = bid >> 3;       // q 0..127
    int i = q & 31, g = q >> 5;          // g 0..3
    int s = (g << 3) + c;
    int si = (s << 5) + i;
    int t = threadIdx.x;
    __shared__ float rx[32], ry[32];
    __shared__ float m0s[512], m1s[512];
    for (int u = t; u < 512; u += 256) { m0s[u] = Mp[u]; m1s[u] = Mp[512 + u]; }
    if (t < 32) {
        int jg = (s << 5) + t;
        float dx = curr[jg * 2] - curr[si * 2];
        float dy = curr[jg * 2 + 1] - curr[si * 2 + 1];
        float den = fmaxf(sqrtf(dx * dx + dy * dy), 1e-12f);
        rx[t] = dx / den; ry[t] = dy / den;
    }
    __syncthreads();
    int j = t >> 3, c8 = t & 7;
    float rxv = rx[j], ryv = ry[j];
    const float* hp = Hp + (((s << 5) + j) << 9);
    unsigned short* op = x1g + ((size_t)((si << 5) + j) << 9);
    int swz = (c8 ^ (j & 7)) << 3;
#pragma unroll
    for (int kt = 0; kt < 512; kt += 64) {
        int k = kt + (c8 << 3);
        float4 ha = *(const float4*)(hp + k);
        float4 hb = *(const float4*)(hp + k + 4);
        uint4 o;
        o.x = pack2(f2bf(fmaxf(fmaf(rxv, m0s[k + 0], fmaf(ryv, m1s[k + 0], ha.x)), 0.f)),
                    f2bf(fmaxf(fmaf(rxv, m0s[k + 1], fmaf(ryv, m1s[k + 1], ha.y)), 0.f)));
        o.y = pack2(f2bf(fmaxf(fmaf(rxv, m0s[k + 2], fmaf(ryv, m1s[k + 2], ha.z)), 0.f)),
                    f2bf(fmaxf(fmaf(rxv, m0s[k + 3], fmaf(ryv, m1s[k + 3], ha.w)), 0.f)));
        o.z = pack2(f2bf(fmaxf(fmaf(rxv, m0s[k + 4], fmaf(ryv, m1s[k + 4], hb.x)), 0.f)),
                    f2bf(fmaxf(fmaf(rxv, m0s[k + 5], fmaf(ryv, m1s[k + 5], hb.y)), 0.f)));
        o.w = pack2(f2bf(fmaxf(fmaf(rxv, m0s[k + 6], fmaf(ryv, m1s[k + 6], hb.z)), 0.f)),
                    f2bf(fmaxf(fmaf(rxv, m0s[k + 7], fmaf(ryv, m1s[k + 7], hb.w)), 0.f)));
        *(uint4*)(op + kt + swz) = o;
    }
}

// Pure GEMM + max-pool. 256x256 tile, 1024 threads (16 waves), BK=64, K=512,
// double-buffered async staging. XCD-swizzled linear grid (512). Pool output packed.
__global__ __launch_bounds__(1024, 4) void k_pool_g(
    const unsigned short* __restrict__ x1g, const unsigned short* __restrict__ W2bf,
    const float* __restrict__ c2v,
    unsigned int* __restrict__ poolp) {
    int bid = blockIdx.x;
    int c = bid & 7, q = bid >> 3;       // q 0..63
    int inner = q & 15, g = q >> 4;      // g 0..3
    int s = (g << 3) + c;
    int rb = inner >> 2;                 // 256-row group (8 i's)
    int koB = (inner & 3) << 8;          // 0,256,512,768
    int t = threadIdx.x;
    int lane = t & 63, wv = t >> 6;      // 16 waves
    int quad = lane >> 4, l15 = lane & 15;
    int wr = wv >> 2, wc = wv & 3;
    int qrow = wr << 6, qcol = wc << 6;
    __shared__ unsigned short As[2][256 * 64];
    __shared__ unsigned short Bs[2][256 * 64];
    f32x4 acc[4][4];
#pragma unroll
    for (int a = 0; a < 4; a++)
#pragma unroll
        for (int b = 0; b < 4; b++) acc[a][b] = (f32x4){0.f, 0.f, 0.f, 0.f};

    int rlane = lane >> 3;               // 0..7
    int clane = (lane & 7) << 3;         // k-chunk (shorts)
    const unsigned short* gA = x1g + (size_t)((s << 10) + (rb << 8) + (wv << 4) + rlane) * 512 + clane;
    const unsigned short* gB = W2bf + (size_t)(koB + (wv << 4) + rlane) * 512 + clane;
    // hoisted fragment bases (kt-invariant): pos = ((kt2<<2)+quad) ^ (l15&7)
    const unsigned short* pa0 = &As[0][((qrow + l15) << 6) + ((quad ^ (l15 & 7)) << 3)];
    const unsigned short* pb0 = &Bs[0][((qcol + l15) << 6) + ((quad ^ (l15 & 7)) << 3)];
    const unsigned short* pa1 = &As[0][((qrow + l15) << 6) + (((4 + quad) ^ (l15 & 7)) << 3)];
    const unsigned short* pb1 = &Bs[0][((qcol + l15) << 6) + (((4 + quad) ^ (l15 & 7)) << 3)];

#define POOL_STAGE(kt, buf)                                           \
    do {                                                              \
        unsigned short* lA = &As[buf][wv << 10];                      \
        unsigned short* lB = &Bs[buf][wv << 10];                      \
        ASYNC_COPY16(gA + (kt), lA);                                  \
        ASYNC_COPY16(gA + (kt) + 8 * 512, lA + (8 << 6));             \
        ASYNC_COPY16(gB + (kt), lB);                                  \
        ASYNC_COPY16(gB + (kt) + 8 * 512, lB + (8 << 6));             \
    } while (0)

    POOL_STAGE(0, 0);
    __syncthreads();
    for (int i = 0; i < 8; i++) {
        if (i < 7) POOL_STAGE((i + 1) << 6, (i + 1) & 1);
        int off = (i & 1) << 14;       // buffer stride 256*64 shorts
        short8 aF[4], bF[4];
#pragma unroll
        for (int a = 0; a < 4; a++) aF[a] = *(const short8*)(pa0 + off + (a << 10));
#pragma unroll
        for (int b = 0; b < 4; b++) bF[b] = *(const short8*)(pb0 + off + (b << 10));
#pragma unroll
        for (int a = 0; a < 4; a++)
#pragma unroll
            for (int b = 0; b < 4; b++)
                acc[a][b] = __builtin_amdgcn_mfma_f32_16x16x32_bf16(aF[a], bF[b], acc[a][b], 0, 0, 0);
#pragma unroll
        for (int a = 0; a < 4; a++) aF[a] = *(const short8*)(pa1 + off + (a << 10));
#pragma unroll
        for (int b = 0; b < 4; b++) bF[b] = *(const short8*)(pb1 + off + (b << 10));
#pragma unroll
        for (int a = 0; a < 4; a++)
#pragma unroll
            for (int b = 0; b < 4; b++)
                acc[a][b] = __builtin_amdgcn_mfma_f32_16x16x32_bf16(aF[a], bF[b], acc[a][b], 0, 0, 0);
        __syncthreads();
    }
#undef POOL_STAGE

    float mx0[4], mx1[4];
#pragma unroll
    for (int b = 0; b < 4; b++) {
        float m = acc[0][b].x;
#pragma unroll
        for (int a = 0; a < 2; a++) {
            m = fmaxf(m, acc[a][b].x); m = fmaxf(m, acc[a][b].y);
            m = fmaxf(m, acc[a][b].z); m = fmaxf(m, acc[a][b].w);
        }
        m = fmaxf(m, __shfl_xor(m, 16));
        m = fmaxf(m, __shfl_xor(m, 32));
        mx0[b] = m;
        float n = acc[2][b].x;
#pragma unroll
        for (int a = 2; a < 4; a++) {
            n = fmaxf(n, acc[a][b].x); n = fmaxf(n, acc[a][b].y);
            n = fmaxf(n, acc[a][b].z); n = fmaxf(n, acc[a][b].w);
        }
        n = fmaxf(n, __shfl_xor(n, 16));
        n = fmaxf(n, __shfl_xor(n, 32));
        mx1[b] = n;
    }
    float v0 = (quad == 0) ? mx0[0] : (quad == 1) ? mx0[1] : (quad == 2) ? mx0[2] : mx0[3];
    float v1 = (quad == 0) ? mx1[0] : (quad == 1) ? mx1[1] : (quad == 2) ? mx1[2] : mx1[3];
    int col = koB + qcol + (quad << 4) + l15;
    int i0 = (rb << 3) + (wr << 1);
    int si0 = (s << 5) + i0;
    float bias = c2v[col];
    poolp[si0 * 1024 + col] = packsplit(fmaxf(v0 + bias, 0.f));
    poolp[(si0 + 1) * 1024 + col] = packsplit(fmaxf(v1 + bias, 0.f));
}

// m1 via bf16x3 MFMA. Block: 64 rows x 64 ko, BK=64, K=1152, sync staging from
// PACKED operands. Grid dim3(16,16): x=ko-group, y=row-group.
__global__ __launch_bounds__(256) void k_m1_mfma(
    const unsigned int* __restrict__ h2p, const unsigned int* __restrict__ poolp,
    const unsigned int* __restrict__ M1p, const float* __restrict__ cm1,
    unsigned int* __restrict__ dh1p) {
    int rowBase = blockIdx.y << 6;
    int koBase = blockIdx.x << 6;
    int t = threadIdx.x;
    int lane = t & 63, wv = t >> 6;
    int quad = lane >> 4, l15 = lane & 15;
    int qrow = (wv >> 1) << 5, qcol = (wv & 1) << 5;
    __shared__ unsigned short Ah[64 * 72], Al[64 * 72], Bh[64 * 72], Bl[64 * 72];
    f32x4 acc[2][2];
#pragma unroll
    for (int a = 0; a < 2; a++)
#pragma unroll
        for (int b = 0; b < 2; b++) acc[a][b] = (f32x4){0.f, 0.f, 0.f, 0.f};

    int ar = t >> 2, ak = (t & 3) << 4;   // 64 rows x 64 k, 16 k-elements/thread

    for (int kt = 0; kt < 1152; kt += 64) {
        {
            const unsigned int* srcA = (kt < 128)
                ? h2p + (rowBase + ar) * 128 + kt + ak
                : poolp + (rowBase + ar) * 1024 + (kt - 128) + ak;
            uint4 a0 = ((const uint4*)srcA)[0];
            uint4 a1 = ((const uint4*)srcA)[1];
            uint4 a2 = ((const uint4*)srcA)[2];
            uint4 a3 = ((const uint4*)srcA)[3];
            const unsigned int* srcB = M1p + (koBase + ar) * 1152 + kt + ak;
            uint4 b0 = ((const uint4*)srcB)[0];
            uint4 b1 = ((const uint4*)srcB)[1];
            uint4 b2 = ((const uint4*)srcB)[2];
            uint4 b3 = ((const uint4*)srcB)[3];
            unzip16(&Ah[ar * 72 + ak], &Al[ar * 72 + ak], a0, a1, a2, a3);
            unzip16(&Bh[ar * 72 + ak], &Bl[ar * 72 + ak], b0, b1, b2, b3);
        }
        __syncthreads();
#pragma unroll
        for (int kk2 = 0; kk2 < 2; kk2++) {
            int kc = ((kk2 << 2) | quad) << 3;
            short8 bH[2], bL[2];
#pragma unroll
            for (int b = 0; b < 2; b++) {
                int boff = (qcol + (b << 4) + l15) * 72 + kc;
                bH[b] = *(const short8*)(&Bh[boff]);
                bL[b] = *(const short8*)(&Bl[boff]);
            }
#pragma unroll
            for (int a = 0; a < 2; a++) {
                int aoff = (qrow + (a << 4) + l15) * 72 + kc;
                short8 aH = *(const short8*)(&Ah[aoff]);
                short8 aL = *(const short8*)(&Al[aoff]);
#pragma unroll
                for (int b = 0; b < 2; b++) {
                    acc[a][b] = __builtin_amdgcn_mfma_f32_16x16x32_bf16(aH, bH[b], acc[a][b], 0, 0, 0);
                    acc[a][b] = __builtin_amdgcn_mfma_f32_16x16x32_bf16(aH, bL[b], acc[a][b], 0, 0, 0);
                    acc[a][b] = __builtin_amdgcn_mfma_f32_16x16x32_bf16(aL, bH[b], acc[a][b], 0, 0, 0);
                }
            }
        }
        __syncthreads();
    }
#pragma unroll
    for (int b = 0; b < 2; b++) {
        int col = koBase + qcol + (b << 4) + l15;
        float bias = cm1[col];
#pragma unroll
        for (int a = 0; a < 2; a++) {
#pragma unroll
            for (int rg = 0; rg < 4; rg++) {
                int row = rowBase + qrow + (a << 4) + (quad << 2) + rg;
                dh1p[row * 1024 + col] = packsplit(fmaxf(acc[a][b][rg] + bias, 0.f));
            }
        }
    }
}

// m2 via bf16x3 MFMA: Block: 32 rows x 128 ko, K=1024. Grid 32. Packed operands.
__global__ __launch_bounds__(256) void k_m2_mfma(
    const unsigned int* __restrict__ dh1p, const unsigned int* __restrict__ M2p,
    const float* __restrict__ cm2, float* __restrict__ h_st) {
    int rowBase = blockIdx.x << 5;
    int t = threadIdx.x;
    int lane = t & 63, wv = t >> 6;
    int quad = lane >> 4, l15 = lane & 15;
    int qrow = (wv >> 1) << 4;   // 0 or 16
    int qcol = (wv & 1) << 6;    // 0 or 64
    __shared__ unsigned short Ah[32 * 40], Al[32 * 40], Bh[128 * 40], Bl[128 * 40];
    f32x4 acc[4];
#pragma unroll
    for (int b = 0; b < 4; b++) acc[b] = (f32x4){0.f, 0.f, 0.f, 0.f};

    int ar = t >> 3, ak = (t & 7) << 2;   // A: 32 rows x 32 k, 4 elements/thread
    int br = t >> 1, bk = (t & 1) << 4;   // B: 128 ko x 32 k, 16 elements/thread

    for (int kt = 0; kt < 1024; kt += 32) {
        {
            uint4 av = *(const uint4*)(dh1p + (rowBase + ar) * 1024 + kt + ak);
            uint2 hi = make_uint2((av.x & 0xffffu) | (av.y << 16),
                                  (av.z & 0xffffu) | (av.w << 16));
            uint2 lo = make_uint2((av.x >> 16) | (av.y & 0xffff0000u),
                                  (av.z >> 16) | (av.w & 0xffff0000u));
            *(uint2*)&Ah[ar * 40 + ak] = hi;
            *(uint2*)&Al[ar * 40 + ak] = lo;
        }
        {
            const unsigned int* srcB = M2p + br * 1024 + kt + bk;
            uint4 b0 = ((const uint4*)srcB)[0];
            uint4 b1 = ((const uint4*)srcB)[1];
            uint4 b2 = ((const uint4*)srcB)[2];
            uint4 b3 = ((const uint4*)srcB)[3];
            unzip16(&Bh[br * 40 + bk], &Bl[br * 40 + bk], b0, b1, b2, b3);
        }
        __syncthreads();
        {
            int aoff = (qrow + l15) * 40 + (quad << 3);
            short8 aH = *(const short8*)(&Ah[aoff]);
            short8 aL = *(const short8*)(&Al[aoff]);
#pragma unroll
            for (int b = 0; b < 4; b++) {
                int boff = (qcol + (b << 4) + l15) * 40 + (quad << 3);
                short8 bH = *(const short8*)(&Bh[boff]);
                short8 bL = *(const short8*)(&Bl[boff]);
                acc[b] = __builtin_amdgcn_mfma_f32_16x16x32_bf16(aH, bH, acc[b], 0, 0, 0);
                acc[b] = __builtin_amdgcn_mfma_f32_16x16x32_bf16(aH, bL, acc[b], 0, 0, 0);
                acc[b] = __builtin_amdgcn_mfma_f32_16x16x32_bf16(aL, bH, acc[b], 0, 0, 0);
            }
        }
        __syncthreads();
    }
#pragma unroll
    for (int b = 0; b < 4; b++) {
        int col = qcol + (b << 4) + l15;
        float bias = cm2[col];
#pragma unroll
        for (int rg = 0; rg < 4; rg++) {
            int row = rowBase + qrow + (quad << 2) + rg;
            h_st[row * 128 + col] = fmaxf(acc[b][rg] + bias, 0.f);
        }
    }
}

// ---------------- launch ----------------

extern "C" void kernel_launch(void* const* d_in, const int* in_sizes, int n_in,
                              void* d_out, int out_size, void* d_ws, size_t ws_size,
                              hipStream_t stream) {
    const float* last_pos     = (const float*)d_in[0];
    const float* last_pos_rel = (const float*)d_in[1];
    const float* h0   = (const float*)d_in[2];
    const float* c0   = (const float*)d_in[3];
    const float* emb_W = (const float*)d_in[5];
    const float* emb_b = (const float*)d_in[6];
    const float* lstm_Wih = (const float*)d_in[7];
    const float* lstm_Whh = (const float*)d_in[8];
    const float* lstm_bih = (const float*)d_in[9];
    const float* lstm_bhh = (const float*)d_in[10];
    const float* pos_W = (const float*)d_in[11];
    const float* pos_b = (const float*)d_in[12];
    const float* sp_W  = (const float*)d_in[13];
    const float* sp_b  = (const float*)d_in[14];
    const float* pp1_W = (const float*)d_in[15];
    const float* pp1_b = (const float*)d_in[16];
    const float* pp1_g = (const float*)d_in[17];
    const float* pp1_be= (const float*)d_in[18];
    const float* pp2_W = (const float*)d_in[19];
    const float* pp2_b = (const float*)d_in[20];
    const float* pp2_g = (const float*)d_in[21];
    const float* pp2_be= (const float*)d_in[22];
    const float* m1_W  = (const float*)d_in[23];
    const float* m1_b  = (const float*)d_in[24];
    const float* m1_g  = (const float*)d_in[25];
    const float* m1_be = (const float*)d_in[26];
    const float* m2_W  = (const float*)d_in[27];
    const float* m2_b  = (const float*)d_in[28];
    const float* m2_g  = (const float*)d_in[29];
    const float* m2_be = (const float*)d_in[30];
    float* out = (float*)d_out;

    float* p = (float*)d_ws;
    float* WgT  = p; p += 192 * 512;
    float* bg   = p; p += 512;
    float* Wh1T = p; p += 128 * 512;
    float* Mp   = p; p += 2 * 512;
    float* c1   = p; p += 512;
    unsigned short* W2bf = (unsigned short*)p; p += 512 * 1024 / 2;
    float* c2v  = p; p += 1024;
    unsigned int* M1p = (unsigned int*)p; p += 1024 * 1152;
    float* cm1  = p; p += 1024;
    unsigned int* M2p = (unsigned int*)p; p += 128 * 1024;
    float* cm2  = p; p += 128;
    float* h_st = p; p += 1024 * 128;
    float* c_st = p; p += 1024 * 128;
    unsigned int* h2p = (unsigned int*)p; p += 1024 * 128;
    float* curr = p; p += 1024 * 2;
    float* din  = p; p += 1024 * 64;
    float* Hp   = p; p += 1024 * 512;
    unsigned int* poolp = (unsigned int*)p; p += 1024 * 1024;
    unsigned int* dh1p = (unsigned int*)p; p += 1024 * 1024;
    unsigned short* x1g = (unsigned short*)p; p += 32768 * 512;  // 33.5 MB

    pre_misc<<<1154, 256, 0, stream>>>(lstm_Wih, lstm_Whh, lstm_bih, lstm_bhh, WgT, bg,
                                       pp1_W, pp1_g, Wh1T,
                                       sp_W, sp_b, pp1_b, pp1_be, Mp, c1,
                                       last_pos, last_pos_rel, h0, c0, emb_W, emb_b,
                                       h_st, c_st, curr, din);
    pre_w<<<7168, 256, 0, stream>>>(pp2_W, pp2_b, pp2_g, pp2_be, W2bf, c2v,
                                    m1_W, m1_b, m1_g, m1_be, M1p, cm1,
                                    m2_W, m2_b, m2_g, m2_be, M2p, cm2);

    for (int t = 0; t < 12; t++) {
        k_lstm<<<256, 512, 0, stream>>>(WgT, bg, h_st, c_st, din, curr, h2p,
                                        pos_W, pos_b, emb_W, emb_b,
                                        Wh1T, c1, Hp, (t < 11) ? 1 : 0, out + t * 2048);
        if (t == 11) break;
        k_x1<<<1024, 256, 0, stream>>>(Hp, Mp, curr, x1g);
        k_pool_g<<<512, 1024, 0, stream>>>(x1g, W2bf, c2v, poolp);
        k_m1_mfma<<<dim3(16, 16), 256, 0, stream>>>(h2p, poolp, M1p, cm1, dh1p);
        k_m2_mfma<<<32, 256, 0, stream>>>(dh1p, M2p, cm2, h_st);
    }
}

// Round 12
// 1380.203 us; speedup vs baseline: 1.3191x; 1.0832x over previous
//
#include <hip/hip_runtime.h>
#include <hip/hip_bf16.h>
#include <math.h>

#define DEVFN __device__ __forceinline__

constexpr float BN_INV = 0.99999500003749971f; // 1/sqrt(1+1e-5)

DEVFN float sigm(float x) { return 1.0f / (1.0f + expf(-x)); }

DEVFN unsigned short f2bf(float f) {
    __hip_bfloat16 b = __float2bfloat16(f);
    return *reinterpret_cast<unsigned short*>(&b);
}
DEVFN float bf2f(unsigned short u) {
    unsigned int x = ((unsigned int)u) << 16;
    return *reinterpret_cast<float*>(&x);
}
DEVFN void splitf(float v, unsigned short& h, unsigned short& l) {
    h = f2bf(v);
    l = f2bf(v - bf2f(h));
}
DEVFN unsigned int pack2(unsigned short a, unsigned short b) {
    return (unsigned int)a | ((unsigned int)b << 16);
}

typedef __attribute__((ext_vector_type(8))) short short8;  // 8 bf16 = 4 VGPRs
typedef __attribute__((ext_vector_type(4))) float f32x4;

// async global->LDS, 16B per lane; ldst must be wave-uniform (HW adds lane*16)
#define ASYNC_COPY16(gsrc, ldst)                                                            \
    __builtin_amdgcn_global_load_lds((const __attribute__((address_space(1))) unsigned int*)(gsrc), \
                                     (__attribute__((address_space(3))) unsigned int*)(ldst), 16, 0, 0)

// ---------------- precompute kernels (run every call; ws is re-poisoned) ----------------

// Merged small precompute: [0,384) lstm-weight transpose, [384,640) wh1,
// [640,642) Mp/c1, [642,1154) state init.
__global__ void pre_misc(
    const float* __restrict__ Wih, const float* __restrict__ Whh,
    const float* __restrict__ bih, const float* __restrict__ bhh,
    float* __restrict__ WgT, float* __restrict__ bg,
    const float* __restrict__ pp1W, const float* __restrict__ pp1g,
    float* __restrict__ Wh1T,
    const float* __restrict__ spW, const float* __restrict__ spb,
    const float* __restrict__ pp1b, const float* __restrict__ pp1be,
    float* __restrict__ Mp, float* __restrict__ c1,
    const float* __restrict__ lp, const float* __restrict__ lpr,
    const float* __restrict__ h0, const float* __restrict__ c0,
    const float* __restrict__ embW, const float* __restrict__ embb,
    float* __restrict__ h_st, float* __restrict__ c_st,
    float* __restrict__ curr, float* __restrict__ din) {
    int bid = blockIdx.x, t = threadIdx.x;
    if (bid < 384) {
        int idx = bid * 256 + t;           // 192*512
        int k = idx >> 9, tt = idx & 511;
        WgT[idx] = (k < 64) ? Wih[tt * 64 + k] : Whh[tt * 128 + (k - 64)];
        if (idx < 512) bg[idx] = bih[idx] + bhh[idx];
    } else if (bid < 640) {
        int idx = (bid - 384) * 256 + t;   // 128*512
        int h = idx >> 9, k = idx & 511;
        Wh1T[idx] = pp1W[k * 192 + 64 + h] * (BN_INV * pp1g[k]);
    } else if (bid < 642) {
        int k = (bid - 640) * 256 + t;     // 512
        float m0 = 0.f, m1 = 0.f, c0v = 0.f;
        for (int e = 0; e < 64; e++) {
            float w = pp1W[k * 192 + e];
            m0 += spW[e * 2] * w; m1 += spW[e * 2 + 1] * w; c0v += spb[e] * w;
        }
        float s = BN_INV * pp1g[k];
        Mp[k] = m0 * s; Mp[512 + k] = m1 * s;
        c1[k] = (c0v + pp1b[k]) * s + pp1be[k];
    } else {
        int idx = (bid - 642) * 256 + t;   // 1024*128
        h_st[idx] = h0[idx];
        c_st[idx] = c0[idx];
        if (idx < 1024 * 2) curr[idx] = lp[idx];
        if (idx < 1024 * 64) {
            int n = idx >> 6, e = idx & 63;
            din[idx] = fmaf(lpr[n * 2], embW[e * 2], fmaf(lpr[n * 2 + 1], embW[e * 2 + 1], embb[e]));
        }
    }
}

// pp2 weights -> bf16, optionally XOR-swizzled (chunk c of each 64-k tile stored at c^(ko&7))
__global__ void pre_w2bf(const float* __restrict__ W, const float* __restrict__ b,
                         const float* __restrict__ g, const float* __restrict__ be,
                         unsigned short* __restrict__ Wbf, float* __restrict__ cv, int swz) {
    int idx = blockIdx.x * blockDim.x + threadIdx.x;   // 1024*512
    int ko = idx >> 9, k = idx & 511;
    float s = BN_INV * g[ko];
    int outk = swz ? ((k & ~63) | ((((k >> 3) & 7) ^ (ko & 7)) << 3) | (k & 7)) : k;
    Wbf[(ko << 9) + outk] = f2bf(W[idx] * s);
    if (idx < 1024) cv[idx] = b[idx] * s + be[idx];
}

__global__ void pre_w1split(const float* __restrict__ W, const float* __restrict__ b,
                            const float* __restrict__ g, const float* __restrict__ be,
                            unsigned short* __restrict__ Wh, unsigned short* __restrict__ Wl,
                            float* __restrict__ cv) {
    int idx = blockIdx.x * blockDim.x + threadIdx.x;   // 1024*1152
    int ko = idx / 1152;
    float s = BN_INV * g[ko];
    unsigned short h, l;
    splitf(W[idx] * s, h, l);
    Wh[idx] = h; Wl[idx] = l;
    if (idx < 1024) {
        float s2 = BN_INV * g[idx];
        cv[idx] = b[idx] * s2 + be[idx];
    }
}

__global__ void pre_w2split(const float* __restrict__ W, const float* __restrict__ b,
                            const float* __restrict__ g, const float* __restrict__ be,
                            unsigned short* __restrict__ Wh, unsigned short* __restrict__ Wl,
                            float* __restrict__ cv) {
    int idx = blockIdx.x * blockDim.x + threadIdx.x;   // 128*1024
    int ko = idx >> 10;
    float s = BN_INV * g[ko];
    unsigned short h, l;
    splitf(W[idx] * s, h, l);
    Wh[idx] = h; Wl[idx] = l;
    if (idx < 128) {
        float s2 = BN_INV * g[idx];
        cv[idx] = b[idx] * s2 + be[idx];
    }
}

// ---------------- per-step kernels ----------------

// Fused: LSTM cell (4 peds/block) + rel_pos + curr + din2 + preds + Hp (=h2@Wh1T + c1).
__global__ __launch_bounds__(512) void k_lstm(
    const float* __restrict__ WgT, const float* __restrict__ bg,
    float* __restrict__ h_st, float* __restrict__ c_st,
    float* __restrict__ din, float* __restrict__ curr,
    unsigned short* __restrict__ h2h, unsigned short* __restrict__ h2l,
    const float* __restrict__ posW, const float* __restrict__ posb,
    const float* __restrict__ embW, const float* __restrict__ embb,
    const float* __restrict__ Wh1T, const float* __restrict__ c1,
    float* __restrict__ Hp, int doHp,
    float* __restrict__ preds) {
    int n0 = blockIdx.x << 2;
    int t = threadIdx.x;
    __shared__ float xs[4][256];
    __shared__ float gates[4][512];
    __shared__ float h2s[4][128];
    __shared__ float rp[4][2];
#pragma unroll
    for (int u = 0; u < 2; u++) {
        int lin = t + (u << 9);
        int r = lin >> 8, k = lin & 255;
        float v = 0.f;
        if (k < 64) v = din[(n0 + r) * 64 + k];
        else if (k < 192) v = h_st[(n0 + r) * 128 + (k - 64)];
        xs[r][k] = v;
    }
    __syncthreads();
    float a0 = bg[t], a1 = a0, a2 = a0, a3 = a0;
#pragma unroll 4
    for (int k = 0; k < 192; k++) {
        float w = WgT[(k << 9) + t];
        a0 = fmaf(xs[0][k], w, a0);
        a1 = fmaf(xs[1][k], w, a1);
        a2 = fmaf(xs[2][k], w, a2);
        a3 = fmaf(xs[3][k], w, a3);
    }
    gates[0][t] = a0; gates[1][t] = a1; gates[2][t] = a2; gates[3][t] = a3;
    __syncthreads();
    {
        int r = t >> 7, hx = t & 127;
        float ig = sigm(gates[r][hx]);
        float fg = sigm(gates[r][128 + hx]);
        float gg = tanhf(gates[r][256 + hx]);
        float og = sigm(gates[r][384 + hx]);
        float c2 = fmaf(fg, c_st[(n0 + r) * 128 + hx], ig * gg);
        float h2 = og * tanhf(c2);
        c_st[(n0 + r) * 128 + hx] = c2;
        unsigned short sh, sl;
        splitf(h2, sh, sl);
        h2h[(n0 + r) * 128 + hx] = sh;
        h2l[(n0 + r) * 128 + hx] = sl;
        h2s[r][hx] = h2;
    }
    __syncthreads();
    int wv = t >> 6, l = t & 63;
    if (wv < 4) {
        float p0 = fmaf(h2s[wv][l], posW[l], h2s[wv][l + 64] * posW[l + 64]);
        float p1 = fmaf(h2s[wv][l], posW[128 + l], h2s[wv][l + 64] * posW[192 + l]);
#pragma unroll
        for (int off = 32; off > 0; off >>= 1) {
            p0 += __shfl_down(p0, off, 64);
            p1 += __shfl_down(p1, off, 64);
        }
        if (l == 0) { rp[wv][0] = p0 + posb[0]; rp[wv][1] = p1 + posb[1]; }
    }
    __syncthreads();
    if (t < 256) {
        int r = t >> 6, e = t & 63;
        float r0 = rp[r][0], r1 = rp[r][1];
        din[(n0 + r) * 64 + e] = fmaf(r0, embW[e * 2], fmaf(r1, embW[e * 2 + 1], embb[e]));
        if (e == 0) {
            preds[(n0 + r) * 2] = r0; preds[(n0 + r) * 2 + 1] = r1;
            curr[(n0 + r) * 2] += r0; curr[(n0 + r) * 2 + 1] += r1;
        }
    }
    if (doHp) {
        float cc = c1[t];
        float q0 = cc, q1 = cc, q2 = cc, q3 = cc;
#pragma unroll 4
        for (int h = 0; h < 128; h++) {
            float w = Wh1T[(h << 9) + t];
            q0 = fmaf(h2s[0][h], w, q0);
            q1 = fmaf(h2s[1][h], w, q1);
            q2 = fmaf(h2s[2][h], w, q2);
            q3 = fmaf(h2s[3][h], w, q3);
        }
        Hp[((n0 + 0) << 9) + t] = q0;
        Hp[((n0 + 1) << 9) + t] = q1;
        Hp[((n0 + 2) << 9) + t] = q2;
        Hp[((n0 + 3) << 9) + t] = q3;
    }
}

// Build x1 bf16 once per step, XOR-swizzled within each 64-k tile (chunk c at c^(j&7)).
// XCD-swizzled grid: scene s on XCD s%8 so x1 lands in the consumer's L2.
__global__ __launch_bounds__(256) void k_x1(
    const float* __restrict__ Hp, const float* __restrict__ Mp,
    const float* __restrict__ curr, unsigned short* __restrict__ x1g) {
    int bid = blockIdx.x;
    int c = bid & 7, q = bid >> 3;       // q 0..127
    int i = q & 31, g = q >> 5;          // g 0..3
    int s = (g << 3) + c;
    int si = (s << 5) + i;
    int t = threadIdx.x;
    __shared__ float rx[32], ry[32];
    __shared__ float m0s[512], m1s[512];
    for (int u = t; u < 512; u += 256) { m0s[u] = Mp[u]; m1s[u] = Mp[512 + u]; }
    if (t < 32) {
        int jg = (s << 5) + t;
        float dx = curr[jg * 2] - curr[si * 2];
        float dy = curr[jg * 2 + 1] - curr[si * 2 + 1];
        float den = fmaxf(sqrtf(dx * dx + dy * dy), 1e-12f);
        rx[t] = dx / den; ry[t] = dy / den;
    }
    __syncthreads();
    int j = t >> 3, c8 = t & 7;
    float rxv = rx[j], ryv = ry[j];
    const float* hp = Hp + (((s << 5) + j) << 9);
    unsigned short* op = x1g + ((size_t)((si << 5) + j) << 9);
    int swz = (c8 ^ (j & 7)) << 3;
#pragma unroll
    for (int kt = 0; kt < 512; kt += 64) {
        int k = kt + (c8 << 3);
        float4 ha = *(const float4*)(hp + k);
        float4 hb = *(const float4*)(hp + k + 4);
        uint4 o;
        o.x = pack2(f2bf(fmaxf(fmaf(rxv, m0s[k + 0], fmaf(ryv, m1s[k + 0], ha.x)), 0.f)),
                    f2bf(fmaxf(fmaf(rxv, m0s[k + 1], fmaf(ryv, m1s[k + 1], ha.y)), 0.f)));
        o.y = pack2(f2bf(fmaxf(fmaf(rxv, m0s[k + 2], fmaf(ryv, m1s[k + 2], ha.z)), 0.f)),
                    f2bf(fmaxf(fmaf(rxv, m0s[k + 3], fmaf(ryv, m1s[k + 3], ha.w)), 0.f)));
        o.z = pack2(f2bf(fmaxf(fmaf(rxv, m0s[k + 4], fmaf(ryv, m1s[k + 4], hb.x)), 0.f)),
                    f2bf(fmaxf(fmaf(rxv, m0s[k + 5], fmaf(ryv, m1s[k + 5], hb.y)), 0.f)));
        o.w = pack2(f2bf(fmaxf(fmaf(rxv, m0s[k + 6], fmaf(ryv, m1s[k + 6], hb.z)), 0.f)),
                    f2bf(fmaxf(fmaf(rxv, m0s[k + 7], fmaf(ryv, m1s[k + 7], hb.w)), 0.f)));
        *(uint4*)(op + kt + swz) = o;
    }
}

// Pure GEMM + max-pool. 256x256 tile, 1024 threads (16 waves), BK=64, K=512,
// DOUBLE-BUFFERED async staging. XCD-swizzled linear grid (512).
__global__ __launch_bounds__(1024, 4) void k_pool_g(
    const unsigned short* __restrict__ x1g, const unsigned short* __restrict__ W2bf,
    const float* __restrict__ c2v,
    unsigned short* __restrict__ poolh, unsigned short* __restrict__ pooll) {
    int bid = blockIdx.x;
    int c = bid & 7, q = bid >> 3;       // q 0..63
    int inner = q & 15, g = q >> 4;      // g 0..3
    int s = (g << 3) + c;
    int rb = inner >> 2;                 // 256-row group (8 i's)
    int koB = (inner & 3) << 8;          // 0,256,512,768
    int t = threadIdx.x;
    int lane = t & 63, wv = t >> 6;      // 16 waves
    int quad = lane >> 4, l15 = lane & 15;
    int wr = wv >> 2, wc = wv & 3;
    int qrow = wr << 6, qcol = wc << 6;
    __shared__ unsigned short As[2][256 * 64];
    __shared__ unsigned short Bs[2][256 * 64];
    f32x4 acc[4][4];
#pragma unroll
    for (int a = 0; a < 4; a++)
#pragma unroll
        for (int b = 0; b < 4; b++) acc[a][b] = (f32x4){0.f, 0.f, 0.f, 0.f};

    int rlane = lane >> 3;               // 0..7
    int clane = (lane & 7) << 3;         // k-chunk (shorts)
    const unsigned short* gA = x1g + (size_t)((s << 10) + (rb << 8) + (wv << 4) + rlane) * 512 + clane;
    const unsigned short* gB = W2bf + (size_t)(koB + (wv << 4) + rlane) * 512 + clane;
    // hoisted fragment bases (kt-invariant): pos = ((kt2<<2)+quad) ^ (l15&7)
    const unsigned short* pa0 = &As[0][((qrow + l15) << 6) + ((quad ^ (l15 & 7)) << 3)];
    const unsigned short* pb0 = &Bs[0][((qcol + l15) << 6) + ((quad ^ (l15 & 7)) << 3)];
    const unsigned short* pa1 = &As[0][((qrow + l15) << 6) + (((4 + quad) ^ (l15 & 7)) << 3)];
    const unsigned short* pb1 = &Bs[0][((qcol + l15) << 6) + (((4 + quad) ^ (l15 & 7)) << 3)];

#define POOL_STAGE(kt, buf)                                           \
    do {                                                              \
        unsigned short* lA = &As[buf][wv << 10];                      \
        unsigned short* lB = &Bs[buf][wv << 10];                      \
        ASYNC_COPY16(gA + (kt), lA);                                  \
        ASYNC_COPY16(gA + (kt) + 8 * 512, lA + (8 << 6));             \
        ASYNC_COPY16(gB + (kt), lB);                                  \
        ASYNC_COPY16(gB + (kt) + 8 * 512, lB + (8 << 6));             \
    } while (0)

    POOL_STAGE(0, 0);
    __syncthreads();
    for (int i = 0; i < 8; i++) {
        if (i < 7) POOL_STAGE((i + 1) << 6, (i + 1) & 1);
        int off = (i & 1) << 14;       // buffer stride 256*64 shorts
        short8 aF[4], bF[4];
#pragma unroll
        for (int a = 0; a < 4; a++) aF[a] = *(const short8*)(pa0 + off + (a << 10));
#pragma unroll
        for (int b = 0; b < 4; b++) bF[b] = *(const short8*)(pb0 + off + (b << 10));
#pragma unroll
        for (int a = 0; a < 4; a++)
#pragma unroll
            for (int b = 0; b < 4; b++)
                acc[a][b] = __builtin_amdgcn_mfma_f32_16x16x32_bf16(aF[a], bF[b], acc[a][b], 0, 0, 0);
#pragma unroll
        for (int a = 0; a < 4; a++) aF[a] = *(const short8*)(pa1 + off + (a << 10));
#pragma unroll
        for (int b = 0; b < 4; b++) bF[b] = *(const short8*)(pb1 + off + (b << 10));
#pragma unroll
        for (int a = 0; a < 4; a++)
#pragma unroll
            for (int b = 0; b < 4; b++)
                acc[a][b] = __builtin_amdgcn_mfma_f32_16x16x32_bf16(aF[a], bF[b], acc[a][b], 0, 0, 0);
        __syncthreads();
    }
#undef POOL_STAGE

    float mx0[4], mx1[4];
#pragma unroll
    for (int b = 0; b < 4; b++) {
        float m = acc[0][b].x;
#pragma unroll
        for (int a = 0; a < 2; a++) {
            m = fmaxf(m, acc[a][b].x); m = fmaxf(m, acc[a][b].y);
            m = fmaxf(m, acc[a][b].z); m = fmaxf(m, acc[a][b].w);
        }
        m = fmaxf(m, __shfl_xor(m, 16));
        m = fmaxf(m, __shfl_xor(m, 32));
        mx0[b] = m;
        float n = acc[2][b].x;
#pragma unroll
        for (int a = 2; a < 4; a++) {
            n = fmaxf(n, acc[a][b].x); n = fmaxf(n, acc[a][b].y);
            n = fmaxf(n, acc[a][b].z); n = fmaxf(n, acc[a][b].w);
        }
        n = fmaxf(n, __shfl_xor(n, 16));
        n = fmaxf(n, __shfl_xor(n, 32));
        mx1[b] = n;
    }
    float v0 = (quad == 0) ? mx0[0] : (quad == 1) ? mx0[1] : (quad == 2) ? mx0[2] : mx0[3];
    float v1 = (quad == 0) ? mx1[0] : (quad == 1) ? mx1[1] : (quad == 2) ? mx1[2] : mx1[3];
    int col = koB + qcol + (quad << 4) + l15;
    int i0 = (rb << 3) + (wr << 1);
    int si0 = (s << 5) + i0;
    float bias = c2v[col];
    float w0 = fmaxf(v0 + bias, 0.f);
    float w1 = fmaxf(v1 + bias, 0.f);
    unsigned short h0, l0, h1, l1;
    splitf(w0, h0, l0); splitf(w1, h1, l1);
    poolh[si0 * 1024 + col] = h0; pooll[si0 * 1024 + col] = l0;
    poolh[(si0 + 1) * 1024 + col] = h1; pooll[(si0 + 1) * 1024 + col] = l1;
}

// m1 via bf16x3 MFMA. Block: 64 rows x 64 ko, BK=64 (18 stages), K=1152.
__global__ __launch_bounds__(256) void k_m1_mfma(
    const unsigned short* __restrict__ h2h, const unsigned short* __restrict__ h2l,
    const unsigned short* __restrict__ poolh, const unsigned short* __restrict__ pooll,
    const unsigned short* __restrict__ M1h, const unsigned short* __restrict__ M1l,
    const float* __restrict__ cm1,
    unsigned short* __restrict__ dh1h, unsigned short* __restrict__ dh1l) {
    int rowBase = blockIdx.y << 6;
    int koBase = blockIdx.x << 6;
    int t = threadIdx.x;
    int lane = t & 63, wv = t >> 6;
    int quad = lane >> 4, l15 = lane & 15;
    int qrow = (wv >> 1) << 5, qcol = (wv & 1) << 5;
    __shared__ unsigned short Ah[64 * 72], Al[64 * 72], Bh[64 * 72], Bl[64 * 72];
    f32x4 acc[2][2];
#pragma unroll
    for (int a = 0; a < 2; a++)
#pragma unroll
        for (int b = 0; b < 2; b++) acc[a][b] = (f32x4){0.f, 0.f, 0.f, 0.f};

    int ar = t >> 2, ak = (t & 3) << 4;   // 64 rows x 64 k, 16 shorts/thread

    for (int kt = 0; kt < 1152; kt += 64) {
        {
            const unsigned short* sH;
            const unsigned short* sL;
            int off;
            if (kt < 128) {
                off = (rowBase + ar) * 128 + kt + ak;
                sH = h2h; sL = h2l;
            } else {
                off = (rowBase + ar) * 1024 + (kt - 128) + ak;
                sH = poolh; sL = pooll;
            }
            *(uint4*)&Ah[ar * 72 + ak] = *(const uint4*)(sH + off);
            *(uint4*)&Ah[ar * 72 + ak + 8] = *(const uint4*)(sH + off + 8);
            *(uint4*)&Al[ar * 72 + ak] = *(const uint4*)(sL + off);
            *(uint4*)&Al[ar * 72 + ak + 8] = *(const uint4*)(sL + off + 8);
        }
        {
            int boff = (koBase + ar) * 1152 + kt + ak;
            *(uint4*)&Bh[ar * 72 + ak] = *(const uint4*)(M1h + boff);
            *(uint4*)&Bh[ar * 72 + ak + 8] = *(const uint4*)(M1h + boff + 8);
            *(uint4*)&Bl[ar * 72 + ak] = *(const uint4*)(M1l + boff);
            *(uint4*)&Bl[ar * 72 + ak + 8] = *(const uint4*)(M1l + boff + 8);
        }
        __syncthreads();
#pragma unroll
        for (int kk2 = 0; kk2 < 2; kk2++) {
            int kc = ((kk2 << 2) | quad) << 3;
            short8 bH[2], bL[2];
#pragma unroll
            for (int b = 0; b < 2; b++) {
                int boff = (qcol + (b << 4) + l15) * 72 + kc;
                bH[b] = *(const short8*)(&Bh[boff]);
                bL[b] = *(const short8*)(&Bl[boff]);
            }
#pragma unroll
            for (int a = 0; a < 2; a++) {
                int aoff = (qrow + (a << 4) + l15) * 72 + kc;
                short8 aH = *(const short8*)(&Ah[aoff]);
                short8 aL = *(const short8*)(&Al[aoff]);
#pragma unroll
                for (int b = 0; b < 2; b++) {
                    acc[a][b] = __builtin_amdgcn_mfma_f32_16x16x32_bf16(aH, bH[b], acc[a][b], 0, 0, 0);
                    acc[a][b] = __builtin_amdgcn_mfma_f32_16x16x32_bf16(aH, bL[b], acc[a][b], 0, 0, 0);
                    acc[a][b] = __builtin_amdgcn_mfma_f32_16x16x32_bf16(aL, bH[b], acc[a][b], 0, 0, 0);
                }
            }
        }
        __syncthreads();
    }
#pragma unroll
    for (int b = 0; b < 2; b++) {
        int col = koBase + qcol + (b << 4) + l15;
        float bias = cm1[col];
#pragma unroll
        for (int a = 0; a < 2; a++) {
#pragma unroll
            for (int rg = 0; rg < 4; rg++) {
                int row = rowBase + qrow + (a << 4) + (quad << 2) + rg;
                float v = fmaxf(acc[a][b][rg] + bias, 0.f);
                unsigned short sh, sl;
                splitf(v, sh, sl);
                dh1h[row * 1024 + col] = sh;
                dh1l[row * 1024 + col] = sl;
            }
        }
    }
}

// m2 via bf16x3 MFMA: Block: 32 rows x 128 ko, K=1024. Grid 32.
__global__ __launch_bounds__(256) void k_m2_mfma(
    const unsigned short* __restrict__ dh1h, const unsigned short* __restrict__ dh1l,
    const unsigned short* __restrict__ M2h, const unsigned short* __restrict__ M2l,
    const float* __restrict__ cm2, float* __restrict__ h_st) {
    int rowBase = blockIdx.x << 5;
    int t = threadIdx.x;
    int lane = t & 63, wv = t >> 6;
    int quad = lane >> 4, l15 = lane & 15;
    int qrow = (wv >> 1) << 4;   // 0 or 16
    int qcol = (wv & 1) << 6;    // 0 or 64
    __shared__ unsigned short Ah[32 * 40], Al[32 * 40], Bh[128 * 40], Bl[128 * 40];
    f32x4 acc[4];
#pragma unroll
    for (int b = 0; b < 4; b++) acc[b] = (f32x4){0.f, 0.f, 0.f, 0.f};

    int ar = t >> 3, ak = (t & 7) << 2;   // A: 32 rows x 32 k, 4 shorts/thread
    int br = t >> 1, bk = (t & 1) << 4;   // B: 128 ko x 32 k, 16 shorts/thread

    for (int kt = 0; kt < 1024; kt += 32) {
        {
            int off = (rowBase + ar) * 1024 + kt + ak;
            *(uint2*)&Ah[ar * 40 + ak] = *(const uint2*)(dh1h + off);
            *(uint2*)&Al[ar * 40 + ak] = *(const uint2*)(dh1l + off);
        }
        {
            int off = br * 1024 + kt + bk;
            *(uint4*)&Bh[br * 40 + bk] = *(const uint4*)(M2h + off);
            *(uint4*)&Bh[br * 40 + bk + 8] = *(const uint4*)(M2h + off + 8);
            *(uint4*)&Bl[br * 40 + bk] = *(const uint4*)(M2l + off);
            *(uint4*)&Bl[br * 40 + bk + 8] = *(const uint4*)(M2l + off + 8);
        }
        __syncthreads();
        {
            int aoff = (qrow + l15) * 40 + (quad << 3);
            short8 aH = *(const short8*)(&Ah[aoff]);
            short8 aL = *(const short8*)(&Al[aoff]);
#pragma unroll
            for (int b = 0; b < 4; b++) {
                int boff = (qcol + (b << 4) + l15) * 40 + (quad << 3);
                short8 bH = *(const short8*)(&Bh[boff]);
                short8 bL = *(const short8*)(&Bl[boff]);
                acc[b] = __builtin_amdgcn_mfma_f32_16x16x32_bf16(aH, bH, acc[b], 0, 0, 0);
                acc[b] = __builtin_amdgcn_mfma_f32_16x16x32_bf16(aH, bL, acc[b], 0, 0, 0);
                acc[b] = __builtin_amdgcn_mfma_f32_16x16x32_bf16(aL, bH, acc[b], 0, 0, 0);
            }
        }
        __syncthreads();
    }
#pragma unroll
    for (int b = 0; b < 4; b++) {
        int col = qcol + (b << 4) + l15;
        float bias = cm2[col];
#pragma unroll
        for (int rg = 0; rg < 4; rg++) {
            int row = rowBase + qrow + (quad << 2) + rg;
            h_st[row * 128 + col] = fmaxf(acc[b][rg] + bias, 0.f);
        }
    }
}

// ---------------- launch ----------------

extern "C" void kernel_launch(void* const* d_in, const int* in_sizes, int n_in,
                              void* d_out, int out_size, void* d_ws, size_t ws_size,
                              hipStream_t stream) {
    const float* last_pos     = (const float*)d_in[0];
    const float* last_pos_rel = (const float*)d_in[1];
    const float* h0   = (const float*)d_in[2];
    const float* c0   = (const float*)d_in[3];
    const float* emb_W = (const float*)d_in[5];
    const float* emb_b = (const float*)d_in[6];
    const float* lstm_Wih = (const float*)d_in[7];
    const float* lstm_Whh = (const float*)d_in[8];
    const float* lstm_bih = (const float*)d_in[9];
    const float* lstm_bhh = (const float*)d_in[10];
    const float* pos_W = (const float*)d_in[11];
    const float* pos_b = (const float*)d_in[12];
    const float* sp_W  = (const float*)d_in[13];
    const float* sp_b  = (const float*)d_in[14];
    const float* pp1_W = (const float*)d_in[15];
    const float* pp1_b = (const float*)d_in[16];
    const float* pp1_g = (const float*)d_in[17];
    const float* pp1_be= (const float*)d_in[18];
    const float* pp2_W = (const float*)d_in[19];
    const float* pp2_b = (const float*)d_in[20];
    const float* pp2_g = (const float*)d_in[21];
    const float* pp2_be= (const float*)d_in[22];
    const float* m1_W  = (const float*)d_in[23];
    const float* m1_b  = (const float*)d_in[24];
    const float* m1_g  = (const float*)d_in[25];
    const float* m1_be = (const float*)d_in[26];
    const float* m2_W  = (const float*)d_in[27];
    const float* m2_b  = (const float*)d_in[28];
    const float* m2_g  = (const float*)d_in[29];
    const float* m2_be = (const float*)d_in[30];
    float* out = (float*)d_out;

    float* p = (float*)d_ws;
    float* WgT  = p; p += 192 * 512;
    float* bg   = p; p += 512;
    float* Wh1T = p; p += 128 * 512;
    float* Mp   = p; p += 2 * 512;
    float* c1   = p; p += 512;
    unsigned short* W2bf = (unsigned short*)p; p += 512 * 1024 / 2;
    float* c2v  = p; p += 1024;
    unsigned short* M1h = (unsigned short*)p; p += 1024 * 1152 / 2;
    unsigned short* M1l = (unsigned short*)p; p += 1024 * 1152 / 2;
    float* cm1  = p; p += 1024;
    unsigned short* M2h = (unsigned short*)p; p += 128 * 1024 / 2;
    unsigned short* M2l = (unsigned short*)p; p += 128 * 1024 / 2;
    float* cm2  = p; p += 128;
    float* h_st = p; p += 1024 * 128;
    float* c_st = p; p += 1024 * 128;
    unsigned short* h2h = (unsigned short*)p; p += 1024 * 128 / 2;
    unsigned short* h2l = (unsigned short*)p; p += 1024 * 128 / 2;
    float* curr = p; p += 1024 * 2;
    float* din  = p; p += 1024 * 64;
    float* Hp   = p; p += 1024 * 512;
    unsigned short* poolh = (unsigned short*)p; p += 1024 * 1024 / 2;
    unsigned short* pooll = (unsigned short*)p; p += 1024 * 1024 / 2;
    unsigned short* dh1h = (unsigned short*)p; p += 1024 * 1024 / 2;
    unsigned short* dh1l = (unsigned short*)p; p += 1024 * 1024 / 2;
    unsigned short* x1g = (unsigned short*)p; p += 32768 * 512;  // 33.5 MB

    pre_misc<<<1154, 256, 0, stream>>>(lstm_Wih, lstm_Whh, lstm_bih, lstm_bhh, WgT, bg,
                                       pp1_W, pp1_g, Wh1T,
                                       sp_W, sp_b, pp1_b, pp1_be, Mp, c1,
                                       last_pos, last_pos_rel, h0, c0, emb_W, emb_b,
                                       h_st, c_st, curr, din);
    pre_w2bf<<<2048, 256, 0, stream>>>(pp2_W, pp2_b, pp2_g, pp2_be, W2bf, c2v, 1);
    pre_w1split<<<4608, 256, 0, stream>>>(m1_W, m1_b, m1_g, m1_be, M1h, M1l, cm1);
    pre_w2split<<<512, 256, 0, stream>>>(m2_W, m2_b, m2_g, m2_be, M2h, M2l, cm2);

    for (int t = 0; t < 12; t++) {
        k_lstm<<<256, 512, 0, stream>>>(WgT, bg, h_st, c_st, din, curr, h2h, h2l,
                                        pos_W, pos_b, emb_W, emb_b,
                                        Wh1T, c1, Hp, (t < 11) ? 1 : 0, out + t * 2048);
        if (t == 11) break;
        k_x1<<<1024, 256, 0, stream>>>(Hp, Mp, curr, x1g);
        k_pool_g<<<512, 1024, 0, stream>>>(x1g, W2bf, c2v, poolh, pooll);
        k_m1_mfma<<<dim3(16, 16), 256, 0, stream>>>(h2h, h2l, poolh, pooll,
                                                    M1h, M1l, cm1, dh1h, dh1l);
        k_m2_mfma<<<32, 256, 0, stream>>>(dh1h, dh1l, M2h, M2l, cm2, h_st);
    }
}

// Round 13
// 1366.160 us; speedup vs baseline: 1.3327x; 1.0103x over previous
//
#include <hip/hip_runtime.h>
#include <hip/hip_bf16.h>
#include <math.h>

#define DEVFN __device__ __forceinline__

constexpr float BN_INV = 0.99999500003749971f; // 1/sqrt(1+1e-5)

DEVFN float sigm(float x) { return 1.0f / (1.0f + expf(-x)); }

DEVFN unsigned short f2bf(float f) {
    __hip_bfloat16 b = __float2bfloat16(f);
    return *reinterpret_cast<unsigned short*>(&b);
}
DEVFN float bf2f(unsigned short u) {
    unsigned int x = ((unsigned int)u) << 16;
    return *reinterpret_cast<float*>(&x);
}
DEVFN void splitf(float v, unsigned short& h, unsigned short& l) {
    h = f2bf(v);
    l = f2bf(v - bf2f(h));
}
DEVFN unsigned int pack2(unsigned short a, unsigned short b) {
    return (unsigned int)a | ((unsigned int)b << 16);
}
// XOR-swizzle a k-index within its 64-k tile by the row parity (chunk c -> c^(row&7))
DEVFN int swz64(int k, int row) {
    return (k & ~63) | ((((k >> 3) & 7) ^ (row & 7)) << 3) | (k & 7);
}

typedef __attribute__((ext_vector_type(8))) short short8;  // 8 bf16 = 4 VGPRs
typedef __attribute__((ext_vector_type(4))) float f32x4;

// async global->LDS, 16B per lane; ldst must be wave-uniform (HW adds lane*16)
#define ASYNC_COPY16(gsrc, ldst)                                                            \
    __builtin_amdgcn_global_load_lds((const __attribute__((address_space(1))) unsigned int*)(gsrc), \
                                     (__attribute__((address_space(3))) unsigned int*)(ldst), 16, 0, 0)

// ---------------- precompute kernels (run every call; ws is re-poisoned) ----------------

// Merged small precompute: [0,384) lstm-weight transpose, [384,640) wh1,
// [640,642) Mp/c1, [642,1154) state init.
__global__ void pre_misc(
    const float* __restrict__ Wih, const float* __restrict__ Whh,
    const float* __restrict__ bih, const float* __restrict__ bhh,
    float* __restrict__ WgT, float* __restrict__ bg,
    const float* __restrict__ pp1W, const float* __restrict__ pp1g,
    float* __restrict__ Wh1T,
    const float* __restrict__ spW, const float* __restrict__ spb,
    const float* __restrict__ pp1b, const float* __restrict__ pp1be,
    float* __restrict__ Mp, float* __restrict__ c1,
    const float* __restrict__ lp, const float* __restrict__ lpr,
    const float* __restrict__ h0, const float* __restrict__ c0,
    const float* __restrict__ embW, const float* __restrict__ embb,
    float* __restrict__ h_st, float* __restrict__ c_st,
    float* __restrict__ curr, float* __restrict__ din) {
    int bid = blockIdx.x, t = threadIdx.x;
    if (bid < 384) {
        int idx = bid * 256 + t;           // 192*512
        int k = idx >> 9, tt = idx & 511;
        WgT[idx] = (k < 64) ? Wih[tt * 64 + k] : Whh[tt * 128 + (k - 64)];
        if (idx < 512) bg[idx] = bih[idx] + bhh[idx];
    } else if (bid < 640) {
        int idx = (bid - 384) * 256 + t;   // 128*512
        int h = idx >> 9, k = idx & 511;
        Wh1T[idx] = pp1W[k * 192 + 64 + h] * (BN_INV * pp1g[k]);
    } else if (bid < 642) {
        int k = (bid - 640) * 256 + t;     // 512
        float m0 = 0.f, m1 = 0.f, c0v = 0.f;
        for (int e = 0; e < 64; e++) {
            float w = pp1W[k * 192 + e];
            m0 += spW[e * 2] * w; m1 += spW[e * 2 + 1] * w; c0v += spb[e] * w;
        }
        float s = BN_INV * pp1g[k];
        Mp[k] = m0 * s; Mp[512 + k] = m1 * s;
        c1[k] = (c0v + pp1b[k]) * s + pp1be[k];
    } else {
        int idx = (bid - 642) * 256 + t;   // 1024*128
        h_st[idx] = h0[idx];
        c_st[idx] = c0[idx];
        if (idx < 1024 * 2) curr[idx] = lp[idx];
        if (idx < 1024 * 64) {
            int n = idx >> 6, e = idx & 63;
            din[idx] = fmaf(lpr[n * 2], embW[e * 2], fmaf(lpr[n * 2 + 1], embW[e * 2 + 1], embb[e]));
        }
    }
}

// pp2 weights -> bf16, XOR-swizzled (chunk c of each 64-k tile stored at c^(ko&7))
__global__ void pre_w2bf(const float* __restrict__ W, const float* __restrict__ b,
                         const float* __restrict__ g, const float* __restrict__ be,
                         unsigned short* __restrict__ Wbf, float* __restrict__ cv, int swz) {
    int idx = blockIdx.x * blockDim.x + threadIdx.x;   // 1024*512
    int ko = idx >> 9, k = idx & 511;
    float s = BN_INV * g[ko];
    int outk = swz ? swz64(k, ko) : k;
    Wbf[(ko << 9) + outk] = f2bf(W[idx] * s);
    if (idx < 1024) cv[idx] = b[idx] * s + be[idx];
}

// m1 weights split hi/lo, XOR-swizzled per 64-k tile (K=1152 = 18 tiles).
__global__ void pre_w1split(const float* __restrict__ W, const float* __restrict__ b,
                            const float* __restrict__ g, const float* __restrict__ be,
                            unsigned short* __restrict__ Wh, unsigned short* __restrict__ Wl,
                            float* __restrict__ cv) {
    int idx = blockIdx.x * blockDim.x + threadIdx.x;   // 1024*1152
    int ko = idx / 1152;
    int k = idx - ko * 1152;
    float s = BN_INV * g[ko];
    unsigned short h, l;
    splitf(W[idx] * s, h, l);
    int outk = swz64(k, ko);
    Wh[ko * 1152 + outk] = h; Wl[ko * 1152 + outk] = l;
    if (idx < 1024) {
        float s2 = BN_INV * g[idx];
        cv[idx] = b[idx] * s2 + be[idx];
    }
}

__global__ void pre_w2split(const float* __restrict__ W, const float* __restrict__ b,
                            const float* __restrict__ g, const float* __restrict__ be,
                            unsigned short* __restrict__ Wh, unsigned short* __restrict__ Wl,
                            float* __restrict__ cv) {
    int idx = blockIdx.x * blockDim.x + threadIdx.x;   // 128*1024
    int ko = idx >> 10;
    float s = BN_INV * g[ko];
    unsigned short h, l;
    splitf(W[idx] * s, h, l);
    Wh[idx] = h; Wl[idx] = l;
    if (idx < 128) {
        float s2 = BN_INV * g[idx];
        cv[idx] = b[idx] * s2 + be[idx];
    }
}

// ---------------- per-step kernels ----------------

// Fused: LSTM cell (4 peds/block) + rel_pos + curr + din2 + preds + Hp (=h2@Wh1T + c1).
// h2h/h2l stored XOR-swizzled (per 64-k tile, by ped&7) for m1's async staging.
__global__ __launch_bounds__(512) void k_lstm(
    const float* __restrict__ WgT, const float* __restrict__ bg,
    float* __restrict__ h_st, float* __restrict__ c_st,
    float* __restrict__ din, float* __restrict__ curr,
    unsigned short* __restrict__ h2h, unsigned short* __restrict__ h2l,
    const float* __restrict__ posW, const float* __restrict__ posb,
    const float* __restrict__ embW, const float* __restrict__ embb,
    const float* __restrict__ Wh1T, const float* __restrict__ c1,
    float* __restrict__ Hp, int doHp,
    float* __restrict__ preds) {
    int n0 = blockIdx.x << 2;
    int t = threadIdx.x;
    __shared__ float xs[4][256];
    __shared__ float gates[4][512];
    __shared__ float h2s[4][128];
    __shared__ float rp[4][2];
#pragma unroll
    for (int u = 0; u < 2; u++) {
        int lin = t + (u << 9);
        int r = lin >> 8, k = lin & 255;
        float v = 0.f;
        if (k < 64) v = din[(n0 + r) * 64 + k];
        else if (k < 192) v = h_st[(n0 + r) * 128 + (k - 64)];
        xs[r][k] = v;
    }
    __syncthreads();
    float a0 = bg[t], a1 = a0, a2 = a0, a3 = a0;
#pragma unroll 4
    for (int k = 0; k < 192; k++) {
        float w = WgT[(k << 9) + t];
        a0 = fmaf(xs[0][k], w, a0);
        a1 = fmaf(xs[1][k], w, a1);
        a2 = fmaf(xs[2][k], w, a2);
        a3 = fmaf(xs[3][k], w, a3);
    }
    gates[0][t] = a0; gates[1][t] = a1; gates[2][t] = a2; gates[3][t] = a3;
    __syncthreads();
    {
        int r = t >> 7, hx = t & 127;
        int n = n0 + r;
        float ig = sigm(gates[r][hx]);
        float fg = sigm(gates[r][128 + hx]);
        float gg = tanhf(gates[r][256 + hx]);
        float og = sigm(gates[r][384 + hx]);
        float c2 = fmaf(fg, c_st[n * 128 + hx], ig * gg);
        float h2 = og * tanhf(c2);
        c_st[n * 128 + hx] = c2;
        unsigned short sh, sl;
        splitf(h2, sh, sl);
        int sx = swz64(hx, n);
        h2h[n * 128 + sx] = sh;
        h2l[n * 128 + sx] = sl;
        h2s[r][hx] = h2;
    }
    __syncthreads();
    int wv = t >> 6, l = t & 63;
    if (wv < 4) {
        float p0 = fmaf(h2s[wv][l], posW[l], h2s[wv][l + 64] * posW[l + 64]);
        float p1 = fmaf(h2s[wv][l], posW[128 + l], h2s[wv][l + 64] * posW[192 + l]);
#pragma unroll
        for (int off = 32; off > 0; off >>= 1) {
            p0 += __shfl_down(p0, off, 64);
            p1 += __shfl_down(p1, off, 64);
        }
        if (l == 0) { rp[wv][0] = p0 + posb[0]; rp[wv][1] = p1 + posb[1]; }
    }
    __syncthreads();
    if (t < 256) {
        int r = t >> 6, e = t & 63;
        float r0 = rp[r][0], r1 = rp[r][1];
        din[(n0 + r) * 64 + e] = fmaf(r0, embW[e * 2], fmaf(r1, embW[e * 2 + 1], embb[e]));
        if (e == 0) {
            preds[(n0 + r) * 2] = r0; preds[(n0 + r) * 2 + 1] = r1;
            curr[(n0 + r) * 2] += r0; curr[(n0 + r) * 2 + 1] += r1;
        }
    }
    if (doHp) {
        float cc = c1[t];
        float q0 = cc, q1 = cc, q2 = cc, q3 = cc;
#pragma unroll 4
        for (int h = 0; h < 128; h++) {
            float w = Wh1T[(h << 9) + t];
            q0 = fmaf(h2s[0][h], w, q0);
            q1 = fmaf(h2s[1][h], w, q1);
            q2 = fmaf(h2s[2][h], w, q2);
            q3 = fmaf(h2s[3][h], w, q3);
        }
        Hp[((n0 + 0) << 9) + t] = q0;
        Hp[((n0 + 1) << 9) + t] = q1;
        Hp[((n0 + 2) << 9) + t] = q2;
        Hp[((n0 + 3) << 9) + t] = q3;
    }
}

// Build x1 bf16 once per step, XOR-swizzled within each 64-k tile (chunk c at c^(j&7)).
// XCD-swizzled grid: scene s on XCD s%8 so x1 lands in the consumer's L2.
__global__ __launch_bounds__(256) void k_x1(
    const float* __restrict__ Hp, const float* __restrict__ Mp,
    const float* __restrict__ curr, unsigned short* __restrict__ x1g) {
    int bid = blockIdx.x;
    int c = bid & 7, q = bid >> 3;       // q 0..127
    int i = q & 31, g = q >> 5;          // g 0..3
    int s = (g << 3) + c;
    int si = (s << 5) + i;
    int t = threadIdx.x;
    __shared__ float rx[32], ry[32];
    __shared__ float m0s[512], m1s[512];
    for (int u = t; u < 512; u += 256) { m0s[u] = Mp[u]; m1s[u] = Mp[512 + u]; }
    if (t < 32) {
        int jg = (s << 5) + t;
        float dx = curr[jg * 2] - curr[si * 2];
        float dy = curr[jg * 2 + 1] - curr[si * 2 + 1];
        float den = fmaxf(sqrtf(dx * dx + dy * dy), 1e-12f);
        rx[t] = dx / den; ry[t] = dy / den;
    }
    __syncthreads();
    int j = t >> 3, c8 = t & 7;
    float rxv = rx[j], ryv = ry[j];
    const float* hp = Hp + (((s << 5) + j) << 9);
    unsigned short* op = x1g + ((size_t)((si << 5) + j) << 9);
    int swz = (c8 ^ (j & 7)) << 3;
#pragma unroll
    for (int kt = 0; kt < 512; kt += 64) {
        int k = kt + (c8 << 3);
        float4 ha = *(const float4*)(hp + k);
        float4 hb = *(const float4*)(hp + k + 4);
        uint4 o;
        o.x = pack2(f2bf(fmaxf(fmaf(rxv, m0s[k + 0], fmaf(ryv, m1s[k + 0], ha.x)), 0.f)),
                    f2bf(fmaxf(fmaf(rxv, m0s[k + 1], fmaf(ryv, m1s[k + 1], ha.y)), 0.f)));
        o.y = pack2(f2bf(fmaxf(fmaf(rxv, m0s[k + 2], fmaf(ryv, m1s[k + 2], ha.z)), 0.f)),
                    f2bf(fmaxf(fmaf(rxv, m0s[k + 3], fmaf(ryv, m1s[k + 3], ha.w)), 0.f)));
        o.z = pack2(f2bf(fmaxf(fmaf(rxv, m0s[k + 4], fmaf(ryv, m1s[k + 4], hb.x)), 0.f)),
                    f2bf(fmaxf(fmaf(rxv, m0s[k + 5], fmaf(ryv, m1s[k + 5], hb.y)), 0.f)));
        o.w = pack2(f2bf(fmaxf(fmaf(rxv, m0s[k + 6], fmaf(ryv, m1s[k + 6], hb.z)), 0.f)),
                    f2bf(fmaxf(fmaf(rxv, m0s[k + 7], fmaf(ryv, m1s[k + 7], hb.w)), 0.f)));
        *(uint4*)(op + kt + swz) = o;
    }
}

// Pure GEMM + max-pool. 256x256 tile, 1024 threads (16 waves), BK=64, K=512,
// DOUBLE-BUFFERED async staging. XCD-swizzled linear grid (512).
// Pool output stored XOR-swizzled (per 64-k tile, by row&7) for m1's async staging.
__global__ __launch_bounds__(1024, 4) void k_pool_g(
    const unsigned short* __restrict__ x1g, const unsigned short* __restrict__ W2bf,
    const float* __restrict__ c2v,
    unsigned short* __restrict__ poolh, unsigned short* __restrict__ pooll) {
    int bid = blockIdx.x;
    int c = bid & 7, q = bid >> 3;       // q 0..63
    int inner = q & 15, g = q >> 4;      // g 0..3
    int s = (g << 3) + c;
    int rb = inner >> 2;                 // 256-row group (8 i's)
    int koB = (inner & 3) << 8;          // 0,256,512,768
    int t = threadIdx.x;
    int lane = t & 63, wv = t >> 6;      // 16 waves
    int quad = lane >> 4, l15 = lane & 15;
    int wr = wv >> 2, wc = wv & 3;
    int qrow = wr << 6, qcol = wc << 6;
    __shared__ unsigned short As[2][256 * 64];
    __shared__ unsigned short Bs[2][256 * 64];
    f32x4 acc[4][4];
#pragma unroll
    for (int a = 0; a < 4; a++)
#pragma unroll
        for (int b = 0; b < 4; b++) acc[a][b] = (f32x4){0.f, 0.f, 0.f, 0.f};

    int rlane = lane >> 3;               // 0..7
    int clane = (lane & 7) << 3;         // k-chunk (shorts)
    const unsigned short* gA = x1g + (size_t)((s << 10) + (rb << 8) + (wv << 4) + rlane) * 512 + clane;
    const unsigned short* gB = W2bf + (size_t)(koB + (wv << 4) + rlane) * 512 + clane;
    // hoisted fragment bases (kt-invariant): pos = ((kt2<<2)+quad) ^ (l15&7)
    const unsigned short* pa0 = &As[0][((qrow + l15) << 6) + ((quad ^ (l15 & 7)) << 3)];
    const unsigned short* pb0 = &Bs[0][((qcol + l15) << 6) + ((quad ^ (l15 & 7)) << 3)];
    const unsigned short* pa1 = &As[0][((qrow + l15) << 6) + (((4 + quad) ^ (l15 & 7)) << 3)];
    const unsigned short* pb1 = &Bs[0][((qcol + l15) << 6) + (((4 + quad) ^ (l15 & 7)) << 3)];

#define POOL_STAGE(kt, buf)                                           \
    do {                                                              \
        unsigned short* lA = &As[buf][wv << 10];                      \
        unsigned short* lB = &Bs[buf][wv << 10];                      \
        ASYNC_COPY16(gA + (kt), lA);                                  \
        ASYNC_COPY16(gA + (kt) + 8 * 512, lA + (8 << 6));             \
        ASYNC_COPY16(gB + (kt), lB);                                  \
        ASYNC_COPY16(gB + (kt) + 8 * 512, lB + (8 << 6));             \
    } while (0)

    POOL_STAGE(0, 0);
    __syncthreads();
    for (int i = 0; i < 8; i++) {
        if (i < 7) POOL_STAGE((i + 1) << 6, (i + 1) & 1);
        int off = (i & 1) << 14;       // buffer stride 256*64 shorts
        short8 aF[4], bF[4];
#pragma unroll
        for (int a = 0; a < 4; a++) aF[a] = *(const short8*)(pa0 + off + (a << 10));
#pragma unroll
        for (int b = 0; b < 4; b++) bF[b] = *(const short8*)(pb0 + off + (b << 10));
#pragma unroll
        for (int a = 0; a < 4; a++)
#pragma unroll
            for (int b = 0; b < 4; b++)
                acc[a][b] = __builtin_amdgcn_mfma_f32_16x16x32_bf16(aF[a], bF[b], acc[a][b], 0, 0, 0);
#pragma unroll
        for (int a = 0; a < 4; a++) aF[a] = *(const short8*)(pa1 + off + (a << 10));
#pragma unroll
        for (int b = 0; b < 4; b++) bF[b] = *(const short8*)(pb1 + off + (b << 10));
#pragma unroll
        for (int a = 0; a < 4; a++)
#pragma unroll
            for (int b = 0; b < 4; b++)
                acc[a][b] = __builtin_amdgcn_mfma_f32_16x16x32_bf16(aF[a], bF[b], acc[a][b], 0, 0, 0);
        __syncthreads();
    }
#undef POOL_STAGE

    float mx0[4], mx1[4];
#pragma unroll
    for (int b = 0; b < 4; b++) {
        float m = acc[0][b].x;
#pragma unroll
        for (int a = 0; a < 2; a++) {
            m = fmaxf(m, acc[a][b].x); m = fmaxf(m, acc[a][b].y);
            m = fmaxf(m, acc[a][b].z); m = fmaxf(m, acc[a][b].w);
        }
        m = fmaxf(m, __shfl_xor(m, 16));
        m = fmaxf(m, __shfl_xor(m, 32));
        mx0[b] = m;
        float n = acc[2][b].x;
#pragma unroll
        for (int a = 2; a < 4; a++) {
            n = fmaxf(n, acc[a][b].x); n = fmaxf(n, acc[a][b].y);
            n = fmaxf(n, acc[a][b].z); n = fmaxf(n, acc[a][b].w);
        }
        n = fmaxf(n, __shfl_xor(n, 16));
        n = fmaxf(n, __shfl_xor(n, 32));
        mx1[b] = n;
    }
    float v0 = (quad == 0) ? mx0[0] : (quad == 1) ? mx0[1] : (quad == 2) ? mx0[2] : mx0[3];
    float v1 = (quad == 0) ? mx1[0] : (quad == 1) ? mx1[1] : (quad == 2) ? mx1[2] : mx1[3];
    int col = koB + qcol + (quad << 4) + l15;
    int i0 = (rb << 3) + (wr << 1);
    int si0 = (s << 5) + i0;
    float bias = c2v[col];
    float w0 = fmaxf(v0 + bias, 0.f);
    float w1 = fmaxf(v1 + bias, 0.f);
    unsigned short h0, l0, h1, l1;
    splitf(w0, h0, l0); splitf(w1, h1, l1);
    int col0 = swz64(col, si0);
    int col1 = swz64(col, si0 + 1);
    poolh[si0 * 1024 + col0] = h0; pooll[si0 * 1024 + col0] = l0;
    poolh[(si0 + 1) * 1024 + col1] = h1; pooll[(si0 + 1) * 1024 + col1] = l1;
}

// m1 via bf16x3 MFMA. Block: 64 rows x 64 ko, BK=64 (18 stages), K=1152.
// Async global_load_lds staging from XOR-swizzled operands, double-buffered.
__global__ __launch_bounds__(256) void k_m1_mfma(
    const unsigned short* __restrict__ h2h, const unsigned short* __restrict__ h2l,
    const unsigned short* __restrict__ poolh, const unsigned short* __restrict__ pooll,
    const unsigned short* __restrict__ M1h, const unsigned short* __restrict__ M1l,
    const float* __restrict__ cm1,
    unsigned short* __restrict__ dh1h, unsigned short* __restrict__ dh1l) {
    int rowBase = blockIdx.y << 6;
    int koBase = blockIdx.x << 6;
    int t = threadIdx.x;
    int lane = t & 63, wv = t >> 6;
    int quad = lane >> 4, l15 = lane & 15;
    int qrow = (wv >> 1) << 5, qcol = (wv & 1) << 5;
    __shared__ unsigned short Ah[2][64 * 64], Al[2][64 * 64];
    __shared__ unsigned short Bh[2][64 * 64], Bl[2][64 * 64];
    f32x4 acc[2][2];
#pragma unroll
    for (int a = 0; a < 2; a++)
#pragma unroll
        for (int b = 0; b < 2; b++) acc[a][b] = (f32x4){0.f, 0.f, 0.f, 0.f};

    int rlane = lane >> 3;               // 0..7
    int clane = (lane & 7) << 3;         // k-chunk (shorts)
    int ar0 = (wv << 4) + rlane;         // first row this lane stages
    const unsigned short* gBh = M1h + (size_t)(koBase + ar0) * 1152 + clane;
    const unsigned short* gBl = M1l + (size_t)(koBase + ar0) * 1152 + clane;

    // hoisted fragment bases (kt-invariant): chunk = ((kk2<<2)|quad) ^ (l15&7)
    const unsigned short* pAh0 = &Ah[0][((qrow + l15) << 6) + ((quad ^ (l15 & 7)) << 3)];
    const unsigned short* pAl0 = &Al[0][((qrow + l15) << 6) + ((quad ^ (l15 & 7)) << 3)];
    const unsigned short* pBh0 = &Bh[0][((qcol + l15) << 6) + ((quad ^ (l15 & 7)) << 3)];
    const unsigned short* pBl0 = &Bl[0][((qcol + l15) << 6) + ((quad ^ (l15 & 7)) << 3)];
    const unsigned short* pAh1 = &Ah[0][((qrow + l15) << 6) + (((4 + quad) ^ (l15 & 7)) << 3)];
    const unsigned short* pAl1 = &Al[0][((qrow + l15) << 6) + (((4 + quad) ^ (l15 & 7)) << 3)];
    const unsigned short* pBh1 = &Bh[0][((qcol + l15) << 6) + (((4 + quad) ^ (l15 & 7)) << 3)];
    const unsigned short* pBl1 = &Bl[0][((qcol + l15) << 6) + (((4 + quad) ^ (l15 & 7)) << 3)];

#define M1_STAGE(kt, buf)                                                            \
    do {                                                                             \
        const unsigned short *sAh, *sAl; size_t abase; int astr;                     \
        if ((kt) < 128) { sAh = h2h; sAl = h2l;                                      \
            abase = (size_t)rowBase * 128 + (kt); astr = 128; }                      \
        else { sAh = poolh; sAl = pooll;                                             \
            abase = (size_t)rowBase * 1024 + ((kt) - 128); astr = 1024; }            \
        unsigned short* dAh = &Ah[buf][wv << 10];                                    \
        unsigned short* dAl = &Al[buf][wv << 10];                                    \
        unsigned short* dBh = &Bh[buf][wv << 10];                                    \
        unsigned short* dBl = &Bl[buf][wv << 10];                                    \
        ASYNC_COPY16(sAh + abase + (size_t)ar0 * astr + clane, dAh);                 \
        ASYNC_COPY16(sAh + abase + (size_t)(ar0 + 8) * astr + clane, dAh + (8 << 6)); \
        ASYNC_COPY16(sAl + abase + (size_t)ar0 * astr + clane, dAl);                 \
        ASYNC_COPY16(sAl + abase + (size_t)(ar0 + 8) * astr + clane, dAl + (8 << 6)); \
        ASYNC_COPY16(gBh + (kt), dBh);                                               \
        ASYNC_COPY16(gBh + (kt) + 8 * 1152, dBh + (8 << 6));                         \
        ASYNC_COPY16(gBl + (kt), dBl);                                               \
        ASYNC_COPY16(gBl + (kt) + 8 * 1152, dBl + (8 << 6));                         \
    } while (0)

    M1_STAGE(0, 0);
    __syncthreads();
    for (int i = 0; i < 18; i++) {
        if (i < 17) M1_STAGE((i + 1) << 6, (i + 1) & 1);
        int off = (i & 1) << 12;       // buffer stride 64*64 shorts
#pragma unroll
        for (int kk2 = 0; kk2 < 2; kk2++) {
            const unsigned short* pah = kk2 ? pAh1 : pAh0;
            const unsigned short* pal = kk2 ? pAl1 : pAl0;
            const unsigned short* pbh = kk2 ? pBh1 : pBh0;
            const unsigned short* pbl = kk2 ? pBl1 : pBl0;
            short8 bH[2], bL[2];
#pragma unroll
            for (int b = 0; b < 2; b++) {
                bH[b] = *(const short8*)(pbh + off + (b << 10));
                bL[b] = *(const short8*)(pbl + off + (b << 10));
            }
#pragma unroll
            for (int a = 0; a < 2; a++) {
                short8 aH = *(const short8*)(pah + off + (a << 10));
                short8 aL = *(const short8*)(pal + off + (a << 10));
#pragma unroll
                for (int b = 0; b < 2; b++) {
                    acc[a][b] = __builtin_amdgcn_mfma_f32_16x16x32_bf16(aH, bH[b], acc[a][b], 0, 0, 0);
                    acc[a][b] = __builtin_amdgcn_mfma_f32_16x16x32_bf16(aH, bL[b], acc[a][b], 0, 0, 0);
                    acc[a][b] = __builtin_amdgcn_mfma_f32_16x16x32_bf16(aL, bH[b], acc[a][b], 0, 0, 0);
                }
            }
        }
        __syncthreads();
    }
#undef M1_STAGE
#pragma unroll
    for (int b = 0; b < 2; b++) {
        int col = koBase + qcol + (b << 4) + l15;
        float bias = cm1[col];
#pragma unroll
        for (int a = 0; a < 2; a++) {
#pragma unroll
            for (int rg = 0; rg < 4; rg++) {
                int row = rowBase + qrow + (a << 4) + (quad << 2) + rg;
                float v = fmaxf(acc[a][b][rg] + bias, 0.f);
                unsigned short sh, sl;
                splitf(v, sh, sl);
                dh1h[row * 1024 + col] = sh;
                dh1l[row * 1024 + col] = sl;
            }
        }
    }
}

// m2 via bf16x3 MFMA: Block: 32 rows x 128 ko, K=1024. Grid 32.
__global__ __launch_bounds__(256) void k_m2_mfma(
    const unsigned short* __restrict__ dh1h, const unsigned short* __restrict__ dh1l,
    const unsigned short* __restrict__ M2h, const unsigned short* __restrict__ M2l,
    const float* __restrict__ cm2, float* __restrict__ h_st) {
    int rowBase = blockIdx.x << 5;
    int t = threadIdx.x;
    int lane = t & 63, wv = t >> 6;
    int quad = lane >> 4, l15 = lane & 15;
    int qrow = (wv >> 1) << 4;   // 0 or 16
    int qcol = (wv & 1) << 6;    // 0 or 64
    __shared__ unsigned short Ah[32 * 40], Al[32 * 40], Bh[128 * 40], Bl[128 * 40];
    f32x4 acc[4];
#pragma unroll
    for (int b = 0; b < 4; b++) acc[b] = (f32x4){0.f, 0.f, 0.f, 0.f};

    int ar = t >> 3, ak = (t & 7) << 2;   // A: 32 rows x 32 k, 4 shorts/thread
    int br = t >> 1, bk = (t & 1) << 4;   // B: 128 ko x 32 k, 16 shorts/thread

    for (int kt = 0; kt < 1024; kt += 32) {
        {
            int off = (rowBase + ar) * 1024 + kt + ak;
            *(uint2*)&Ah[ar * 40 + ak] = *(const uint2*)(dh1h + off);
            *(uint2*)&Al[ar * 40 + ak] = *(const uint2*)(dh1l + off);
        }
        {
            int off = br * 1024 + kt + bk;
            *(uint4*)&Bh[br * 40 + bk] = *(const uint4*)(M2h + off);
            *(uint4*)&Bh[br * 40 + bk + 8] = *(const uint4*)(M2h + off + 8);
            *(uint4*)&Bl[br * 40 + bk] = *(const uint4*)(M2l + off);
            *(uint4*)&Bl[br * 40 + bk + 8] = *(const uint4*)(M2l + off + 8);
        }
        __syncthreads();
        {
            int aoff = (qrow + l15) * 40 + (quad << 3);
            short8 aH = *(const short8*)(&Ah[aoff]);
            short8 aL = *(const short8*)(&Al[aoff]);
#pragma unroll
            for (int b = 0; b < 4; b++) {
                int boff = (qcol + (b << 4) + l15) * 40 + (quad << 3);
                short8 bH = *(const short8*)(&Bh[boff]);
                short8 bL = *(const short8*)(&Bl[boff]);
                acc[b] = __builtin_amdgcn_mfma_f32_16x16x32_bf16(aH, bH, acc[b], 0, 0, 0);
                acc[b] = __builtin_amdgcn_mfma_f32_16x16x32_bf16(aH, bL, acc[b], 0, 0, 0);
                acc[b] = __builtin_amdgcn_mfma_f32_16x16x32_bf16(aL, bH, acc[b], 0, 0, 0);
            }
        }
        __syncthreads();
    }
#pragma unroll
    for (int b = 0; b < 4; b++) {
        int col = qcol + (b << 4) + l15;
        float bias = cm2[col];
#pragma unroll
        for (int rg = 0; rg < 4; rg++) {
            int row = rowBase + qrow + (quad << 2) + rg;
            h_st[row * 128 + col] = fmaxf(acc[b][rg] + bias, 0.f);
        }
    }
}

// ---------------- launch ----------------

extern "C" void kernel_launch(void* const* d_in, const int* in_sizes, int n_in,
                              void* d_out, int out_size, void* d_ws, size_t ws_size,
                              hipStream_t stream) {
    const float* last_pos     = (const float*)d_in[0];
    const float* last_pos_rel = (const float*)d_in[1];
    const float* h0   = (const float*)d_in[2];
    const float* c0   = (const float*)d_in[3];
    const float* emb_W = (const float*)d_in[5];
    const float* emb_b = (const float*)d_in[6];
    const float* lstm_Wih = (const float*)d_in[7];
    const float* lstm_Whh = (const float*)d_in[8];
    const float* lstm_bih = (const float*)d_in[9];
    const float* lstm_bhh = (const float*)d_in[10];
    const float* pos_W = (const float*)d_in[11];
    const float* pos_b = (const float*)d_in[12];
    const float* sp_W  = (const float*)d_in[13];
    const float* sp_b  = (const float*)d_in[14];
    const float* pp1_W = (const float*)d_in[15];
    const float* pp1_b = (const float*)d_in[16];
    const float* pp1_g = (const float*)d_in[17];
    const float* pp1_be= (const float*)d_in[18];
    const float* pp2_W = (const float*)d_in[19];
    const float* pp2_b = (const float*)d_in[20];
    const float* pp2_g = (const float*)d_in[21];
    const float* pp2_be= (const float*)d_in[22];
    const float* m1_W  = (const float*)d_in[23];
    const float* m1_b  = (const float*)d_in[24];
    const float* m1_g  = (const float*)d_in[25];
    const float* m1_be = (const float*)d_in[26];
    const float* m2_W  = (const float*)d_in[27];
    const float* m2_b  = (const float*)d_in[28];
    const float* m2_g  = (const float*)d_in[29];
    const float* m2_be = (const float*)d_in[30];
    float* out = (float*)d_out;

    float* p = (float*)d_ws;
    float* WgT  = p; p += 192 * 512;
    float* bg   = p; p += 512;
    float* Wh1T = p; p += 128 * 512;
    float* Mp   = p; p += 2 * 512;
    float* c1   = p; p += 512;
    unsigned short* W2bf = (unsigned short*)p; p += 512 * 1024 / 2;
    float* c2v  = p; p += 1024;
    unsigned short* M1h = (unsigned short*)p; p += 1024 * 1152 / 2;
    unsigned short* M1l = (unsigned short*)p; p += 1024 * 1152 / 2;
    float* cm1  = p; p += 1024;
    unsigned short* M2h = (unsigned short*)p; p += 128 * 1024 / 2;
    unsigned short* M2l = (unsigned short*)p; p += 128 * 1024 / 2;
    float* cm2  = p; p += 128;
    float* h_st = p; p += 1024 * 128;
    float* c_st = p; p += 1024 * 128;
    unsigned short* h2h = (unsigned short*)p; p += 1024 * 128 / 2;
    unsigned short* h2l = (unsigned short*)p; p += 1024 * 128 / 2;
    float* curr = p; p += 1024 * 2;
    float* din  = p; p += 1024 * 64;
    float* Hp   = p; p += 1024 * 512;
    unsigned short* poolh = (unsigned short*)p; p += 1024 * 1024 / 2;
    unsigned short* pooll = (unsigned short*)p; p += 1024 * 1024 / 2;
    unsigned short* dh1h = (unsigned short*)p; p += 1024 * 1024 / 2;
    unsigned short* dh1l = (unsigned short*)p; p += 1024 * 1024 / 2;
    unsigned short* x1g = (unsigned short*)p; p += 32768 * 512;  // 33.5 MB

    pre_misc<<<1154, 256, 0, stream>>>(lstm_Wih, lstm_Whh, lstm_bih, lstm_bhh, WgT, bg,
                                       pp1_W, pp1_g, Wh1T,
                                       sp_W, sp_b, pp1_b, pp1_be, Mp, c1,
                                       last_pos, last_pos_rel, h0, c0, emb_W, emb_b,
                                       h_st, c_st, curr, din);
    pre_w2bf<<<2048, 256, 0, stream>>>(pp2_W, pp2_b, pp2_g, pp2_be, W2bf, c2v, 1);
    pre_w1split<<<4608, 256, 0, stream>>>(m1_W, m1_b, m1_g, m1_be, M1h, M1l, cm1);
    pre_w2split<<<512, 256, 0, stream>>>(m2_W, m2_b, m2_g, m2_be, M2h, M2l, cm2);

    for (int t = 0; t < 12; t++) {
        k_lstm<<<256, 512, 0, stream>>>(WgT, bg, h_st, c_st, din, curr, h2h, h2l,
                                        pos_W, pos_b, emb_W, emb_b,
                                        Wh1T, c1, Hp, (t < 11) ? 1 : 0, out + t * 2048);
        if (t == 11) break;
        k_x1<<<1024, 256, 0, stream>>>(Hp, Mp, curr, x1g);
        k_pool_g<<<512, 1024, 0, stream>>>(x1g, W2bf, c2v, poolh, pooll);
        k_m1_mfma<<<dim3(16, 16), 256, 0, stream>>>(h2h, h2l, poolh, pooll,
                                                    M1h, M1l, cm1, dh1h, dh1l);
        k_m2_mfma<<<32, 256, 0, stream>>>(dh1h, dh1l, M2h, M2l, cm2, h_st);
    }
}